// Round 8
// baseline (2813.098 us; speedup 1.0000x reference)
//
#include <hip/hip_runtime.h>
#include <hip/hip_bf16.h>
#include <cstdint>

#define DD 20
#define HID 30
#define NB_SCAN 1024
#define HROW 32   // bf16 hidden row stride (64 B, one cacheline)

typedef unsigned int  u32;
typedef unsigned short u16;

__device__ __forceinline__ void load20(const float* __restrict__ p, float* r){
  const float4* q = (const float4*)p;
#pragma unroll
  for (int i=0;i<5;i++){ float4 v=q[i]; r[4*i+0]=v.x; r[4*i+1]=v.y; r[4*i+2]=v.z; r[4*i+3]=v.w; }
}

__device__ __forceinline__ u32 pkbf(float a, float b){
  u32 ua=__float_as_uint(a); ua=(ua+0x7FFFu+((ua>>16)&1u))>>16;
  u32 ub=__float_as_uint(b); ub=(ub+0x7FFFu+((ub>>16)&1u))>>16;
  return ua | (ub<<16);
}

__global__ void k_prep(const float* __restrict__ rela, const float* __restrict__ w1,
                       const float* __restrict__ wp, const float* __restrict__ wn,
                       const float* __restrict__ wf,
                       float* __restrict__ W3, float* __restrict__ AR, float* __restrict__ AQ,
                       int nrel){
  int t = blockIdx.x*blockDim.x + threadIdx.x;
  if (t < 3*DD*DD){
    int s = t/(DD*DD), idx = t%(DD*DD);
    W3[t] = (s==0)?wp[idx]:((s==1)?wn[idx]:wf[idx]);
  }
  if (t < nrel*HID){
    int r=t/HID, j=t-r*HID;
    float sr=0.f, sq=0.f;
#pragma unroll
    for (int k=0;k<DD;k++){
      float e = rela[r*DD+k];
      sr += e*w1[j*3*DD + DD + k];
      sq += e*w1[j*3*DD + 2*DD + k];
    }
    AR[r*32+j]=sr; AQ[r*32+j]=sq;
  }
}

__global__ void k_rt(const float* __restrict__ rela, const float* __restrict__ timee,
                     const float* __restrict__ W3, float* __restrict__ RT,
                     int nrel, int ntime){
  int row = blockIdx.x*blockDim.x+threadIdx.x;
  int tot = 3*nrel*ntime;
  if (row>=tot) return;
  int per = nrel*ntime;
  int sel = row/per; int rem = row - sel*per; int r = rem/ntime; int t = rem - r*ntime;
  float e[DD], tv[DD];
  load20(rela + (size_t)r*DD, e);
  load20(timee + (size_t)t*DD, tv);
#pragma unroll
  for (int k=0;k<DD;k++) e[k]+=tv[k];
  const float* W = W3 + sel*DD*DD;
  float o[DD];
#pragma unroll
  for (int i=0;i<DD;i++){
    const float4* wr = (const float4*)(W + i*DD);
    float s=0.f;
#pragma unroll
    for (int c=0;c<5;c++){ float4 w=wr[c]; s += e[4*c]*w.x + e[4*c+1]*w.y + e[4*c+2]*w.z + e[4*c+3]*w.w; }
    o[i]=s;
  }
  float4* op=(float4*)(RT + (size_t)row*DD);
#pragma unroll
  for (int c=0;c<5;c++){ float4 v; v.x=o[4*c]; v.y=o[4*c+1]; v.z=o[4*c+2]; v.w=o[4*c+3]; op[c]=v; }
}

// ---- F0: zero d_out / bf16 bufs / f32 spill buf (even blocks) || layer-0 histogram (odd) ----
__global__ void __launch_bounds__(256) k_pre(const int* __restrict__ dst0, int* __restrict__ cnt0,
        int* __restrict__ rank0, int E,
        float4* __restrict__ dout4, size_t nd4,
        uint4* __restrict__ b0, uint4* __restrict__ b1, size_t nbB4,
        float4* __restrict__ bF, size_t nf4){
  int g=blockIdx.x, tid=threadIdx.x;
  int half=gridDim.x>>1;
  if (g & 1){
    int stride=half*256;
    for (int e=(g>>1)*256+tid; e<E; e+=stride)
      rank0[e]=atomicAdd(&cnt0[dst0[e]],1);
  } else {
    float4 z=make_float4(0.f,0.f,0.f,0.f);
    uint4 zu=make_uint4(0u,0u,0u,0u);
    size_t i=(size_t)(g>>1)*256+tid, st=(size_t)half*256;
    for (size_t k=i;k<nd4;k+=st) dout4[k]=z;
    for (size_t k=i;k<nbB4;k+=st){ b0[k]=zu; b1[k]=zu; }
    for (size_t k=i;k<nf4;k+=st) bF[k]=z;
  }
}

// ---- per-layer scan (N elements) ----
__global__ void k_scan_part(const int* __restrict__ cnt, int* __restrict__ part, int M, int C){
  __shared__ int sm[256];
  int b=blockIdx.x, t=threadIdx.x;
  int lo=b*C, hi=lo+C; if (hi>M) hi=M; if (lo>M) lo=M;
  int s=0;
  for (int i=lo+t; i<hi; i+=256) s+=cnt[i];
  sm[t]=s; __syncthreads();
  for (int o=128;o>0;o>>=1){ if (t<o) sm[t]+=sm[t+o]; __syncthreads(); }
  if (t==0) part[b]=sm[0];
}

__global__ void k_scan_top(int* __restrict__ part, int* __restrict__ listc){
  __shared__ int sm[NB_SCAN];
  int t=threadIdx.x;
  if (t==0) *listc=0;
  int v=part[t]; sm[t]=v; __syncthreads();
  for (int o=1;o<NB_SCAN;o<<=1){
    int u=(t>=o)?sm[t-o]:0; __syncthreads();
    sm[t]+=u; __syncthreads();
  }
  part[t]=sm[t]-v;   // exclusive
}

__global__ void k_scan_write(const int* __restrict__ cnt, const int* __restrict__ part,
                             int* __restrict__ rowptr, int M, int C){
  __shared__ int sm[256];
  int b=blockIdx.x, t=threadIdx.x;
  int lo=b*C, hi=lo+C; if (hi>M) hi=M; if (lo>M) lo=M;
  int run=part[b];
  for (int base=lo; base<hi; base+=256){
    int i=base+t;
    int v=(i<hi)?cnt[i]:0;
    sm[t]=v; __syncthreads();
    for (int o=1;o<256;o<<=1){
      int u=(t>=o)?sm[t-o]:0; __syncthreads();
      sm[t]+=u; __syncthreads();
    }
    if (i<hi) rowptr[i]=run+sm[t]-v;
    int tot=sm[255];
    __syncthreads();
    run+=tot;
  }
  if (hi==M && t==0) rowptr[M]=run;
}

// ---- per-layer scatter to CSR slots; l0 extra blocks fill b_cls into all node output slots ----
__global__ void __launch_bounds__(256) k_scat(const int* __restrict__ src,const int* __restrict__ dst,
  const int* __restrict__ rel,const int* __restrict__ qrel,const int* __restrict__ rtm,
  const int* __restrict__ rank,const int* __restrict__ rowptr,int4* __restrict__ recs,int E,
  int xb,
  float* __restrict__ dout,const int* __restrict__ nb,const int* __restrict__ ne,
  const int* __restrict__ nentp,const float* __restrict__ bcls,int N){
  int g=blockIdx.x, tid=threadIdx.x;
  if (g<xb){
    float b=bcls[0]; long long stride=nentp[0];
    for (int n=g*256+tid;n<N;n+=xb*256) dout[(long long)nb[n]*stride+ne[n]]=b;
    return;
  }
  int e=(g-xb)*256+tid;
  if (e>=E) return;
  int d=dst[e];
  int pos=rowptr[d]+rank[e];
  recs[pos]=make_int4(src[e], rel[e]|(qrel[e]<<16), rtm[e], d);
}

// ---- fused layer: wave-level. Per-edge compute + wave segmented suffix-scan (shuffles),
//      zero LDS, zero barriers. Optionally ∥ next-layer hist; optionally fused final epilogue ----
template<bool HASH,bool HIST,bool FINAL>
__global__ void __launch_bounds__(256,8) k_fused(
    const int4* __restrict__ recs,
    const u16* __restrict__ hin, u16* __restrict__ hout, float* __restrict__ bufF,
    const float* __restrict__ RT, const float* __restrict__ AR, const float* __restrict__ AQ,
    const float* __restrict__ w1, const float* __restrict__ w2, const float* __restrict__ W3,
    int E, int nrel, int ntime,
    const int* __restrict__ ndst, int* __restrict__ ncnt, int* __restrict__ nrank, int nE,
    const float* __restrict__ wcls, const float* __restrict__ bcls,
    const int* __restrict__ nbv, const int* __restrict__ nev, const int* __restrict__ nentp,
    float* __restrict__ outp, int* __restrict__ list, int* __restrict__ listc)
{
  int lb;
  if (HIST){
    int g=blockIdx.x;
    int r3=g%3, b3=g/3;
    if (r3==2){                           // histogram role (next layer)
      int H=gridDim.x/3;
      int stride=H*256;
      for (int e=b3*256+threadIdx.x; e<nE; e+=stride)
        nrank[e]=atomicAdd(&ncnt[ndst[e]],1);
      return;
    }
    lb=b3*2+r3;
  } else lb=blockIdx.x;
  int bstart=lb*256;
  if (bstart>=E) return;

  int tid=threadIdx.x;
  int j=bstart+tid;
  int lane=tid&63;
  int wbase=j-lane;
  if (wbase>=E) return;                  // whole wave past end (no barriers -> safe)
  bool active=(j<E);

  int dprev=-1,dnext=-1;
  if (lane==0 && wbase>0) dprev=recs[wbase-1].w;
  if (lane==1 && wbase+64<E) dnext=recs[wbase+64].w;
  dprev=__shfl(dprev,0);
  dnext=__shfl(dnext,1);

  int dstv=-1;
  float m[DD];
#pragma unroll
  for (int i=0;i<DD;i++) m[i]=0.f;

  if (active){
    int4 rc=recs[j];
    int s = rc.x;
    int r = rc.y & 0xFFFF;
    int q = ((unsigned)rc.y) >> 16;
    int t = rc.z;
    dstv  = rc.w;
    int sel = (t>0)?2:((t==0)?1:0);
    int ta = (t<0)?-t:t;

    float h[DD];
    if (HASH){
      const uint4* hp=(const uint4*)(hin+(size_t)s*HROW);   // 64 B aligned, 1 cacheline
      uint4 A=hp[0], B=hp[1]; uint2 Cc=*((const uint2*)(hp+2));
      u32 w0;
      w0=A.x; h[0]=__uint_as_float(w0<<16); h[1]=__uint_as_float(w0&0xFFFF0000u);
      w0=A.y; h[2]=__uint_as_float(w0<<16); h[3]=__uint_as_float(w0&0xFFFF0000u);
      w0=A.z; h[4]=__uint_as_float(w0<<16); h[5]=__uint_as_float(w0&0xFFFF0000u);
      w0=A.w; h[6]=__uint_as_float(w0<<16); h[7]=__uint_as_float(w0&0xFFFF0000u);
      w0=B.x; h[8]=__uint_as_float(w0<<16); h[9]=__uint_as_float(w0&0xFFFF0000u);
      w0=B.y; h[10]=__uint_as_float(w0<<16); h[11]=__uint_as_float(w0&0xFFFF0000u);
      w0=B.z; h[12]=__uint_as_float(w0<<16); h[13]=__uint_as_float(w0&0xFFFF0000u);
      w0=B.w; h[14]=__uint_as_float(w0<<16); h[15]=__uint_as_float(w0&0xFFFF0000u);
      w0=Cc.x; h[16]=__uint_as_float(w0<<16); h[17]=__uint_as_float(w0&0xFFFF0000u);
      w0=Cc.y; h[18]=__uint_as_float(w0<<16); h[19]=__uint_as_float(w0&0xFFFF0000u);
      // leaky already applied at store time
    }

    // attention: z streamed, no a[30]
    float z=0.f;
    {
      const float4* ap=(const float4*)(AR+(size_t)r*32);
      const float4* qp=(const float4*)(AQ+(size_t)q*32);
#pragma unroll
      for (int c=0;c<7;c++){
        float4 x=ap[c], y=qp[c];
        float s4[4]={x.x+y.x, x.y+y.y, x.z+y.z, x.w+y.w};
        if (HASH){
#pragma unroll
          for (int u=0;u<4;u++){
            const float4* wr=(const float4*)(w1 + (size_t)(4*c+u)*(3*DD));
            float sum=s4[u];
#pragma unroll
            for (int c2=0;c2<5;c2++){ float4 w=wr[c2]; sum += h[4*c2]*w.x+h[4*c2+1]*w.y+h[4*c2+2]*w.z+h[4*c2+3]*w.w; }
            s4[u]=sum;
          }
        }
#pragma unroll
        for (int u=0;u<4;u++) z += fmaxf(s4[u],0.f)*w2[4*c+u];
      }
      float2 x2=*(const float2*)(AR+(size_t)r*32+28);
      float2 y2=*(const float2*)(AQ+(size_t)q*32+28);
      float s0=x2.x+y2.x, s1=x2.y+y2.y;
      if (HASH){
        const float4* wr0=(const float4*)(w1 + (size_t)28*(3*DD));
        const float4* wr1=(const float4*)(w1 + (size_t)29*(3*DD));
#pragma unroll
        for (int c2=0;c2<5;c2++){
          float4 wA=wr0[c2], wB=wr1[c2];
          s0 += h[4*c2]*wA.x+h[4*c2+1]*wA.y+h[4*c2+2]*wA.z+h[4*c2+3]*wA.w;
          s1 += h[4*c2]*wB.x+h[4*c2+1]*wB.y+h[4*c2+2]*wB.z+h[4*c2+3]*wB.w;
        }
      }
      z += fmaxf(s0,0.f)*w2[28] + fmaxf(s1,0.f)*w2[29];
    }
    float score = 1.f/(1.f+__expf(-z));

    // transform: m streamed per float4 chunk
    const float* RTrow = RT + ((size_t)(sel*nrel+r)*ntime + ta)*DD;
    const float* Ws = W3 + sel*DD*DD;
#pragma unroll
    for (int c=0;c<5;c++){
      float4 t4=((const float4*)RTrow)[c];
      float mv[4]={t4.x,t4.y,t4.z,t4.w};
      if (HASH){
#pragma unroll
        for (int u=0;u<4;u++){
          const float4* wr=(const float4*)(Ws+(size_t)(4*c+u)*DD);
          float sum=mv[u];
#pragma unroll
          for (int c2=0;c2<5;c2++){ float4 w=wr[c2]; sum += h[4*c2]*w.x+h[4*c2+1]*w.y+h[4*c2+2]*w.z+h[4*c2+3]*w.w; }
          mv[u]=sum;
        }
      }
#pragma unroll
      for (int u=0;u<4;u++) m[4*c+u]=score*mv[u];
    }
  }

  // wave-level segmented suffix-sum over sorted dst runs
#pragma unroll
  for (int off=1; off<64; off<<=1){
    int nd=__shfl_down(dstv,off);
    bool ok=(lane+off<64)&&(nd==dstv);
#pragma unroll
    for (int i=0;i<DD;i++){
      float nm=__shfl_down(m[i],off);
      m[i] += ok? nm:0.f;
    }
  }

  if (!active) return;
  int prevd=__shfl_up(dstv,1);
  bool isHead = (lane==0) ? (dprev!=dstv) : (prevd!=dstv);

  if (lane==0 && !isHead){
    // continuation of a run begun in an earlier wave: spill suffix, no list (true head listed it)
    float* o=bufF+(size_t)dstv*DD;
#pragma unroll
    for (int i=0;i<DD;i++) atomicAdd(o+i,m[i]);
    return;
  }
  if (!isHead) return;

  bool crossing = (dstv==dnext);         // run continues into next wave (sorted => only last run)
  if (crossing){
    float* o=bufF+(size_t)dstv*DD;
#pragma unroll
    for (int i=0;i<DD;i++) atomicAdd(o+i,m[i]);
    int p=atomicAdd(listc,1);
    list[p]=dstv;
  } else {
    if (!FINAL){
      u32 o10[10];
#pragma unroll
      for (int i2=0;i2<10;i2++){
        float x0=m[2*i2], x1=m[2*i2+1];
        x0=fmaxf(x0,0.01f*x0); x1=fmaxf(x1,0.01f*x1);     // leaky at store
        o10[i2]=pkbf(x0,x1);
      }
      uint4* hp=(uint4*)(hout+(size_t)dstv*HROW);
      hp[0]=make_uint4(o10[0],o10[1],o10[2],o10[3]);
      hp[1]=make_uint4(o10[4],o10[5],o10[6],o10[7]);
      *((uint2*)(hp+2))=make_uint2(o10[8],o10[9]);
    } else {
      float rsum=bcls[0];
#pragma unroll
      for (int i=0;i<DD;i++){ float x=fmaxf(m[i],0.01f*m[i]); rsum += x*wcls[i]; }
      long long stride = nentp[0];
      outp[(long long)nbv[dstv]*stride + nev[dstv]] = rsum;
    }
  }
}

// ---- finish crossing segments: read f32 spill, re-zero it, emit bf16 row (or final score) ----
template<bool FINAL>
__global__ void __launch_bounds__(256) k_fixup(float* __restrict__ bufF, u16* __restrict__ hout,
   const float* __restrict__ wcls,const float* __restrict__ bcls,
   const int* __restrict__ nb,const int* __restrict__ ne,const int* __restrict__ nentp,
   float* __restrict__ out,const int* __restrict__ list,const int* __restrict__ listc){
  int c=*listc;
  for (int i=blockIdx.x*blockDim.x+threadIdx.x; i<c; i+=gridDim.x*blockDim.x){
    int n=list[i];
    float* p=bufF+(size_t)n*DD;
    float v[DD];
#pragma unroll
    for (int jj=0;jj<DD;jj++){ v[jj]=p[jj]; p[jj]=0.f; }
    if (FINAL){
      float rsum=bcls[0];
#pragma unroll
      for (int jj=0;jj<DD;jj++){ float x=fmaxf(v[jj],0.01f*v[jj]); rsum+=x*wcls[jj]; }
      long long stride=nentp[0];
      out[(long long)nb[n]*stride+ne[n]]=rsum;
    } else {
      u32 o10[10];
#pragma unroll
      for (int i2=0;i2<10;i2++){
        float x0=v[2*i2], x1=v[2*i2+1];
        x0=fmaxf(x0,0.01f*x0); x1=fmaxf(x1,0.01f*x1);
        o10[i2]=pkbf(x0,x1);
      }
      uint4* hp=(uint4*)(hout+(size_t)n*HROW);
      hp[0]=make_uint4(o10[0],o10[1],o10[2],o10[3]);
      hp[1]=make_uint4(o10[4],o10[5],o10[6],o10[7]);
      *((uint2*)(hp+2))=make_uint2(o10[8],o10[9]);
    }
  }
}

// ================= fallback (round-2 proven atomic path, f32) =================
template<bool HASH>
__global__ void __launch_bounds__(256) k_edge(
    const int* __restrict__ src, const int* __restrict__ dst,
    const int* __restrict__ rel, const int* __restrict__ qrel,
    const int* __restrict__ rtm,
    const float* __restrict__ hin, float* __restrict__ hout,
    const float* __restrict__ RT, const float* __restrict__ AR, const float* __restrict__ AQ,
    const float* __restrict__ w1, const float* __restrict__ w2, const float* __restrict__ W3,
    int E, int nrel, int ntime)
{
  __shared__ float sW1h[HID*DD];
  __shared__ float sW2[32];
  __shared__ float sW3[3*DD*DD];
  for (int t=threadIdx.x; t<HID*DD; t+=blockDim.x){ int j=t/DD,k=t-j*DD; sW1h[t]=w1[j*3*DD+k]; }
  if (threadIdx.x<HID) sW2[threadIdx.x]=w2[threadIdx.x];
  for (int t=threadIdx.x; t<3*DD*DD; t+=blockDim.x) sW3[t]=W3[t];
  __syncthreads();
  int e = blockIdx.x*blockDim.x+threadIdx.x;
  if (e>=E) return;
  int s=src[e], d=dst[e], r=rel[e], q=qrel[e], t=rtm[e];
  int sel = (t>0)?2:((t==0)?1:0);
  int ta = (t<0)?-t:t;
  float h[DD];
  if (HASH){
    load20(hin+(size_t)s*DD, h);
#pragma unroll
    for (int i=0;i<DD;i++) h[i]=fmaxf(h[i],0.01f*h[i]);
  }
  float a[HID];
  {
    const float4* ap=(const float4*)(AR+(size_t)r*32);
    const float4* qp=(const float4*)(AQ+(size_t)q*32);
#pragma unroll
    for (int c=0;c<7;c++){
      float4 x=ap[c], y=qp[c];
      a[4*c+0]=x.x+y.x; a[4*c+1]=x.y+y.y; a[4*c+2]=x.z+y.z; a[4*c+3]=x.w+y.w;
    }
    float2 x=*(const float2*)(AR+(size_t)r*32+28);
    float2 y=*(const float2*)(AQ+(size_t)q*32+28);
    a[28]=x.x+y.x; a[29]=x.y+y.y;
  }
  if (HASH){
#pragma unroll
    for (int j=0;j<HID;j++){
      const float4* wr=(const float4*)&sW1h[j*DD];
      float sum=a[j];
#pragma unroll
      for (int c=0;c<5;c++){ float4 w=wr[c]; sum += h[4*c]*w.x+h[4*c+1]*w.y+h[4*c+2]*w.z+h[4*c+3]*w.w; }
      a[j]=sum;
    }
  }
  float z=0.f;
#pragma unroll
  for (int j=0;j<HID;j++) z += fmaxf(a[j],0.f)*sW2[j];
  float score = 1.f/(1.f+__expf(-z));
  float tr[DD];
  load20(RT + ((size_t)(sel*nrel+r)*ntime + ta)*DD, tr);
  if (HASH){
    const float* Ws = sW3 + sel*DD*DD;
#pragma unroll
    for (int i=0;i<DD;i++){
      const float4* wr=(const float4*)(Ws+i*DD);
      float sum=tr[i];
#pragma unroll
      for (int c=0;c<5;c++){ float4 w=wr[c]; sum += h[4*c]*w.x+h[4*c+1]*w.y+h[4*c+2]*w.z+h[4*c+3]*w.w; }
      tr[i]=sum;
    }
  }
  float* o = hout + (size_t)d*DD;
#pragma unroll
  for (int i=0;i<DD;i++) atomicAdd(o+i, score*tr[i]);
}

__global__ void k_result(const float* __restrict__ h, const float* __restrict__ wcls,
                         const float* __restrict__ bcls, float* __restrict__ res, int N){
  int i = blockIdx.x*blockDim.x+threadIdx.x;
  if (i>=N) return;
  float acc = bcls[0];
  const float4* q=(const float4*)(h+(size_t)i*DD);
#pragma unroll
  for (int c=0;c<5;c++){
    float4 v=q[c];
    float x0=fmaxf(v.x,0.01f*v.x), x1=fmaxf(v.y,0.01f*v.y);
    float x2=fmaxf(v.z,0.01f*v.z), x3=fmaxf(v.w,0.01f*v.w);
    acc += x0*wcls[4*c]+x1*wcls[4*c+1]+x2*wcls[4*c+2]+x3*wcls[4*c+3];
  }
  res[i]=acc;
}

__global__ void k_scatter(const float* __restrict__ res, const int* __restrict__ nb,
                          const int* __restrict__ ne, const int* __restrict__ nentp,
                          float* __restrict__ out, int N){
  int i=blockIdx.x*blockDim.x+threadIdx.x;
  if (i>=N) return;
  long long stride = nentp[0];
  out[(long long)nb[i]*stride + ne[i]] = res[i];
}

extern "C" void kernel_launch(void* const* d_in, const int* in_sizes, int n_in,
                              void* d_out, int out_size, void* d_ws, size_t ws_size,
                              hipStream_t stream){
  const int*   src =(const int*)d_in[0];
  const int*   dst =(const int*)d_in[1];
  const int*   rel =(const int*)d_in[2];
  const int*   qrel=(const int*)d_in[3];
  const int*   rtm =(const int*)d_in[4];
  const int*   nb  =(const int*)d_in[5];
  const int*   ne  =(const int*)d_in[6];
  const float* rela=(const float*)d_in[7];
  const float* timee=(const float*)d_in[8];
  const float* w1  =(const float*)d_in[9];
  const float* w2  =(const float*)d_in[10];
  const float* wp  =(const float*)d_in[11];
  const float* wn  =(const float*)d_in[12];
  const float* wf  =(const float*)d_in[13];
  const float* wcls=(const float*)d_in[14];
  const float* bcls=(const float*)d_in[15];
  const int*   nentp=(const int*)d_in[17];

  const int Lc=3;
  int LE=in_sizes[0]; int E=LE/Lc;
  int N=in_sizes[5];
  int nrel=in_sizes[7]/DD;
  int ntime=in_sizes[8]/DD;

  auto al=[](size_t x){ return (x+(size_t)255)&~(size_t)255; };
  size_t szBufB=al((size_t)N*HROW*2);              // bf16 hidden, 64 B rows
  size_t szBufF=al((size_t)N*DD*4);                // f32 crossing spill
  size_t szBuf =al((size_t)N*DD*4);                // fallback f32 bufs
  size_t szRT  =al((size_t)3*nrel*ntime*DD*4);
  size_t szA   =al((size_t)nrel*32*4);
  size_t szW3  =al((size_t)3*DD*DD*4);
  size_t szRow =al((size_t)Lc*((size_t)N+1)*4);
  size_t szRank=al((size_t)LE*4);
  size_t szCnt =al((size_t)Lc*N*4);
  size_t szRecs=al((size_t)LE*16);
  size_t szPart=al((size_t)NB_SCAN*4);
  size_t szList=al((size_t)(131072+16)*4);
  size_t need = 2*szBufB+szBufF+szRT+2*szA+szW3+szRow+szRank+szCnt+szRecs+szPart+szList;

  dim3 blk(256);
  int prepTot = (3*DD*DD > nrel*HID) ? 3*DD*DD : nrel*HID;
  int rtTot=3*nrel*ntime;

  if (ws_size >= need){
    char* base=(char*)d_ws;
    size_t off=0;
    u16*   b0 =(u16*)(base+off);   off+=szBufB;
    u16*   b1 =(u16*)(base+off);   off+=szBufB;
    float* bufF=(float*)(base+off); off+=szBufF;
    float* RT  =(float*)(base+off); off+=szRT;
    float* AR  =(float*)(base+off); off+=szA;
    float* AQ  =(float*)(base+off); off+=szA;
    float* W3  =(float*)(base+off); off+=szW3;
    int*   rowptr=(int*)(base+off); off+=szRow;     // Lc*(N+1)
    int*   rank=(int*)(base+off);  off+=szRank;
    int*   cnt =(int*)(base+off);  off+=szCnt;      // Lc*N
    int4*  recs=(int4*)(base+off); off+=szRecs;
    int*   part=(int*)(base+off);  off+=szPart;
    int*   listc=(int*)(base+off);
    int*   list =listc+16;          off+=szList;

    float* dout=(float*)d_out;

    (void)hipMemsetAsync(cnt,0,(size_t)Lc*N*4,stream);
    k_prep<<<dim3((prepTot+255)/256),blk,0,stream>>>(rela,w1,wp,wn,wf,W3,AR,AQ,nrel);
    k_rt<<<dim3((rtTot+255)/256),blk,0,stream>>>(rela,timee,W3,RT,nrel,ntime);

    size_t nd4=(size_t)out_size>>2;
    size_t nbB4=(size_t)N*HROW*2/16;     // uint4 count per bf16 buf
    size_t nf4=(size_t)N*DD/4;
    k_pre<<<dim3(8192),blk,0,stream>>>(dst,cnt,rank,E,(float4*)dout,nd4,
                                       (uint4*)b0,(uint4*)b1,nbB4,(float4*)bufF,nf4);

    int C=(N+NB_SCAN-1)/NB_SCAN;
    int LB=(E+255)/256;
    int H=(LB+1)/2;

    for (int l=0;l<Lc;++l){
      int* cnt_l = cnt + (size_t)l*N;
      int* row_l = rowptr + (size_t)l*(N+1);
      k_scan_part<<<dim3(NB_SCAN),blk,0,stream>>>(cnt_l,part,N,C);
      k_scan_top<<<dim3(1),dim3(NB_SCAN),0,stream>>>(part,listc);
      k_scan_write<<<dim3(NB_SCAN),blk,0,stream>>>(cnt_l,part,row_l,N,C);
      size_t eo=(size_t)l*E;
      int xb = (l==0)?1024:0;
      k_scat<<<dim3(xb+LB),blk,0,stream>>>(src+eo,dst+eo,rel+eo,qrel+eo,rtm+eo,
          rank+eo,row_l,recs+eo,E,xb,dout,nb,ne,nentp,bcls,N);
      if (l==0){
        k_fused<false,true,false><<<dim3(3*H),blk,0,stream>>>(recs,nullptr,b0,bufF,
            RT,AR,AQ,w1,w2,W3,E,nrel,ntime,
            dst+(size_t)E,cnt+(size_t)N,rank+(size_t)E,E,
            nullptr,nullptr,nullptr,nullptr,nullptr,nullptr,list,listc);
        k_fixup<false><<<dim3(128),blk,0,stream>>>(bufF,b0,wcls,bcls,nb,ne,nentp,dout,list,listc);
      } else if (l==1){
        k_fused<true,true,false><<<dim3(3*H),blk,0,stream>>>(recs+(size_t)E,b0,b1,bufF,
            RT,AR,AQ,w1,w2,W3,E,nrel,ntime,
            dst+(size_t)2*E,cnt+(size_t)2*N,rank+(size_t)2*E,E,
            nullptr,nullptr,nullptr,nullptr,nullptr,nullptr,list,listc);
        k_fixup<false><<<dim3(128),blk,0,stream>>>(bufF,b1,wcls,bcls,nb,ne,nentp,dout,list,listc);
      } else {
        k_fused<true,false,true><<<dim3(LB),blk,0,stream>>>(recs+(size_t)2*E,b1,nullptr,bufF,
            RT,AR,AQ,w1,w2,W3,E,nrel,ntime,
            nullptr,nullptr,nullptr,0,
            wcls,bcls,nb,ne,nentp,dout,list,listc);
        k_fixup<true><<<dim3(128),blk,0,stream>>>(bufF,nullptr,wcls,bcls,nb,ne,nentp,dout,list,listc);
      }
    }
  } else {
    // fallback: proven round-2 atomic path (scratch carved from d_out, res in ws)
    char* base=(char*)d_out; float* res=(float*)d_ws;
    size_t off=0;
    float* buf0=(float*)(base+off); off+=szBuf;
    float* buf1=(float*)(base+off); off+=szBuf;
    float* RT  =(float*)(base+off); off+=szRT;
    float* AR  =(float*)(base+off); off+=szA;
    float* AQ  =(float*)(base+off); off+=szA;
    float* W3  =(float*)(base+off); off+=szW3;
    k_prep<<<dim3((prepTot+255)/256),blk,0,stream>>>(rela,w1,wp,wn,wf,W3,AR,AQ,nrel);
    k_rt<<<dim3((rtTot+255)/256),blk,0,stream>>>(rela,timee,W3,RT,nrel,ntime);
    dim3 egrid((E+255)/256);
    dim3 ngrid((N+255)/256);
    (void)hipMemsetAsync(buf0,0,(size_t)N*DD*4,stream);
    k_edge<false><<<egrid,blk,0,stream>>>(src,dst,rel,qrel,rtm,nullptr,buf0,RT,AR,AQ,w1,w2,W3,E,nrel,ntime);
    (void)hipMemsetAsync(buf1,0,(size_t)N*DD*4,stream);
    k_edge<true><<<egrid,blk,0,stream>>>(src+(size_t)E,dst+(size_t)E,rel+(size_t)E,qrel+(size_t)E,rtm+(size_t)E,
                                         buf0,buf1,RT,AR,AQ,w1,w2,W3,E,nrel,ntime);
    (void)hipMemsetAsync(buf0,0,(size_t)N*DD*4,stream);
    k_edge<true><<<egrid,blk,0,stream>>>(src+(size_t)2*E,dst+(size_t)2*E,rel+(size_t)2*E,qrel+(size_t)2*E,rtm+(size_t)2*E,
                                         buf1,buf0,RT,AR,AQ,w1,w2,W3,E,nrel,ntime);
    k_result<<<ngrid,blk,0,stream>>>(buf0,wcls,bcls,res,N);
    (void)hipMemsetAsync(d_out,0,(size_t)out_size*sizeof(float),stream);
    k_scatter<<<ngrid,blk,0,stream>>>(res,nb,ne,nentp,(float*)d_out,N);
  }
}

// Round 9
// 1084.966 us; speedup vs baseline: 2.5928x; 2.5928x over previous
//
#include <hip/hip_runtime.h>
#include <hip/hip_bf16.h>
#include <cstdint>

#define DD 20
#define HID 30
#define NB_SCAN 1024
#define HROW 32   // bf16 hidden row stride (64 B, one cacheline)

typedef unsigned int  u32;
typedef unsigned short u16;

__device__ __forceinline__ void load20(const float* __restrict__ p, float* r){
  const float4* q = (const float4*)p;
#pragma unroll
  for (int i=0;i<5;i++){ float4 v=q[i]; r[4*i+0]=v.x; r[4*i+1]=v.y; r[4*i+2]=v.z; r[4*i+3]=v.w; }
}

__device__ __forceinline__ u32 pkbf(float a, float b){
  u32 ua=__float_as_uint(a); ua=(ua+0x7FFFu+((ua>>16)&1u))>>16;
  u32 ub=__float_as_uint(b); ub=(ub+0x7FFFu+((ub>>16)&1u))>>16;
  return ua | (ub<<16);
}

__global__ void k_prep(const float* __restrict__ rela, const float* __restrict__ w1,
                       const float* __restrict__ wp, const float* __restrict__ wn,
                       const float* __restrict__ wf,
                       float* __restrict__ W3, float* __restrict__ AR, float* __restrict__ AQ,
                       int nrel){
  int t = blockIdx.x*blockDim.x + threadIdx.x;
  if (t < 3*DD*DD){
    int s = t/(DD*DD), idx = t%(DD*DD);
    W3[t] = (s==0)?wp[idx]:((s==1)?wn[idx]:wf[idx]);
  }
  if (t < nrel*HID){
    int r=t/HID, j=t-r*HID;
    float sr=0.f, sq=0.f;
#pragma unroll
    for (int k=0;k<DD;k++){
      float e = rela[r*DD+k];
      sr += e*w1[j*3*DD + DD + k];
      sq += e*w1[j*3*DD + 2*DD + k];
    }
    AR[r*32+j]=sr; AQ[r*32+j]=sq;
  }
}

// f32 RT (fallback path only)
__global__ void k_rt(const float* __restrict__ rela, const float* __restrict__ timee,
                     const float* __restrict__ W3, float* __restrict__ RT,
                     int nrel, int ntime){
  int row = blockIdx.x*blockDim.x+threadIdx.x;
  int tot = 3*nrel*ntime;
  if (row>=tot) return;
  int per = nrel*ntime;
  int sel = row/per; int rem = row - sel*per; int r = rem/ntime; int t = rem - r*ntime;
  float e[DD], tv[DD];
  load20(rela + (size_t)r*DD, e);
  load20(timee + (size_t)t*DD, tv);
#pragma unroll
  for (int k=0;k<DD;k++) e[k]+=tv[k];
  const float* W = W3 + sel*DD*DD;
  float o[DD];
#pragma unroll
  for (int i=0;i<DD;i++){
    const float4* wr = (const float4*)(W + i*DD);
    float s=0.f;
#pragma unroll
    for (int c=0;c<5;c++){ float4 w=wr[c]; s += e[4*c]*w.x + e[4*c+1]*w.y + e[4*c+2]*w.z + e[4*c+3]*w.w; }
    o[i]=s;
  }
  float4* op=(float4*)(RT + (size_t)row*DD);
#pragma unroll
  for (int c=0;c<5;c++){ float4 v; v.x=o[4*c]; v.y=o[4*c+1]; v.z=o[4*c+2]; v.w=o[4*c+3]; op[c]=v; }
}

// packed-bf16 RT: 64 B rows (10 data u32 + 6 pad) -> each gather is exactly 1 cacheline
__global__ void k_rtb(const float* __restrict__ rela, const float* __restrict__ timee,
                      const float* __restrict__ W3, u32* __restrict__ RTb,
                      int nrel, int ntime){
  int row = blockIdx.x*blockDim.x+threadIdx.x;
  int tot = 3*nrel*ntime;
  if (row>=tot) return;
  int per = nrel*ntime;
  int sel = row/per; int rem = row - sel*per; int r = rem/ntime; int t = rem - r*ntime;
  float e[DD], tv[DD];
  load20(rela + (size_t)r*DD, e);
  load20(timee + (size_t)t*DD, tv);
#pragma unroll
  for (int k=0;k<DD;k++) e[k]+=tv[k];
  const float* W = W3 + sel*DD*DD;
  float o[DD];
#pragma unroll
  for (int i=0;i<DD;i++){
    const float4* wr = (const float4*)(W + i*DD);
    float s=0.f;
#pragma unroll
    for (int c=0;c<5;c++){ float4 w=wr[c]; s += e[4*c]*w.x + e[4*c+1]*w.y + e[4*c+2]*w.z + e[4*c+3]*w.w; }
    o[i]=s;
  }
  u32 p10[10];
#pragma unroll
  for (int i2=0;i2<10;i2++) p10[i2]=pkbf(o[2*i2],o[2*i2+1]);
  uint4* op=(uint4*)(RTb + (size_t)row*16);
  op[0]=make_uint4(p10[0],p10[1],p10[2],p10[3]);
  op[1]=make_uint4(p10[4],p10[5],p10[6],p10[7]);
  *((uint2*)(op+2))=make_uint2(p10[8],p10[9]);
}

// ---- F0: zero d_out / bf16 bufs / f32 spill buf (even blocks) || layer-0 histogram (odd) ----
__global__ void __launch_bounds__(256) k_pre(const int* __restrict__ dst0, int* __restrict__ cnt0,
        int* __restrict__ rank0, int E,
        float4* __restrict__ dout4, size_t nd4,
        uint4* __restrict__ b0, uint4* __restrict__ b1, size_t nbB4,
        float4* __restrict__ bF, size_t nf4){
  int g=blockIdx.x, tid=threadIdx.x;
  int half=gridDim.x>>1;
  if (g & 1){
    int stride=half*256;
    for (int e=(g>>1)*256+tid; e<E; e+=stride)
      rank0[e]=atomicAdd(&cnt0[dst0[e]],1);
  } else {
    float4 z=make_float4(0.f,0.f,0.f,0.f);
    uint4 zu=make_uint4(0u,0u,0u,0u);
    size_t i=(size_t)(g>>1)*256+tid, st=(size_t)half*256;
    for (size_t k=i;k<nd4;k+=st) dout4[k]=z;
    for (size_t k=i;k<nbB4;k+=st){ b0[k]=zu; b1[k]=zu; }
    for (size_t k=i;k<nf4;k+=st) bF[k]=z;
  }
}

// ---- per-layer scan (N elements) ----
__global__ void k_scan_part(const int* __restrict__ cnt, int* __restrict__ part, int M, int C){
  __shared__ int sm[256];
  int b=blockIdx.x, t=threadIdx.x;
  int lo=b*C, hi=lo+C; if (hi>M) hi=M; if (lo>M) lo=M;
  int s=0;
  for (int i=lo+t; i<hi; i+=256) s+=cnt[i];
  sm[t]=s; __syncthreads();
  for (int o=128;o>0;o>>=1){ if (t<o) sm[t]+=sm[t+o]; __syncthreads(); }
  if (t==0) part[b]=sm[0];
}

__global__ void k_scan_top(int* __restrict__ part, int* __restrict__ listc){
  __shared__ int sm[NB_SCAN];
  int t=threadIdx.x;
  if (t==0) *listc=0;
  int v=part[t]; sm[t]=v; __syncthreads();
  for (int o=1;o<NB_SCAN;o<<=1){
    int u=(t>=o)?sm[t-o]:0; __syncthreads();
    sm[t]+=u; __syncthreads();
  }
  part[t]=sm[t]-v;   // exclusive
}

__global__ void k_scan_write(const int* __restrict__ cnt, const int* __restrict__ part,
                             int* __restrict__ rowptr, int M, int C){
  __shared__ int sm[256];
  int b=blockIdx.x, t=threadIdx.x;
  int lo=b*C, hi=lo+C; if (hi>M) hi=M; if (lo>M) lo=M;
  int run=part[b];
  for (int base=lo; base<hi; base+=256){
    int i=base+t;
    int v=(i<hi)?cnt[i]:0;
    sm[t]=v; __syncthreads();
    for (int o=1;o<256;o<<=1){
      int u=(t>=o)?sm[t-o]:0; __syncthreads();
      sm[t]+=u; __syncthreads();
    }
    if (i<hi) rowptr[i]=run+sm[t]-v;
    int tot=sm[255];
    __syncthreads();
    run+=tot;
  }
  if (hi==M && t==0) rowptr[M]=run;
}

// ---- per-layer scatter to CSR slots; l0 extra blocks fill b_cls into all node output slots ----
__global__ void __launch_bounds__(256) k_scat(const int* __restrict__ src,const int* __restrict__ dst,
  const int* __restrict__ rel,const int* __restrict__ qrel,const int* __restrict__ rtm,
  const int* __restrict__ rank,const int* __restrict__ rowptr,int4* __restrict__ recs,int E,
  int xb,
  float* __restrict__ dout,const int* __restrict__ nb,const int* __restrict__ ne,
  const int* __restrict__ nentp,const float* __restrict__ bcls,int N){
  int g=blockIdx.x, tid=threadIdx.x;
  if (g<xb){
    float b=bcls[0]; long long stride=nentp[0];
    for (int n=g*256+tid;n<N;n+=xb*256) dout[(long long)nb[n]*stride+ne[n]]=b;
    return;
  }
  int e=(g-xb)*256+tid;
  if (e>=E) return;
  int d=dst[e];
  int pos=rowptr[d]+rank[e];
  recs[pos]=make_int4(src[e], rel[e]|(qrel[e]<<16), rtm[e], d);
}

// ---- fused layer: per-edge compute + LDS(bf16) segmented reduce, bf16 hidden + bf16 RT,
//      optionally ∥ next-layer hist, optionally fused final epilogue ----
template<bool HASH,bool HIST,bool FINAL>
__global__ void __launch_bounds__(256) k_fused(
    const int4* __restrict__ recs,
    const u16* __restrict__ hin, u16* __restrict__ hout, float* __restrict__ bufF,
    const u32* __restrict__ RTb, const float* __restrict__ AR, const float* __restrict__ AQ,
    const float* __restrict__ w1, const float* __restrict__ w2, const float* __restrict__ W3,
    int E, int nrel, int ntime,
    const int* __restrict__ ndst, int* __restrict__ ncnt, int* __restrict__ nrank, int nE,
    const float* __restrict__ wcls, const float* __restrict__ bcls,
    const int* __restrict__ nbv, const int* __restrict__ nev, const int* __restrict__ nentp,
    float* __restrict__ outp, int* __restrict__ list, int* __restrict__ listc)
{
  int lb;
  if (HIST){
    int g=blockIdx.x;
    int r3=g%3, b3=g/3;
    if (r3==2){                           // histogram role (next layer)
      int H=gridDim.x/3;
      int stride=H*256;
      for (int e=b3*256+threadIdx.x; e<nE; e+=stride)
        nrank[e]=atomicAdd(&ncnt[ndst[e]],1);
      return;
    }
    lb=b3*2+r3;
  } else lb=blockIdx.x;
  int bstart=lb*256;
  if (bstart>=E) return;

  __shared__ float sW1h[HID*DD];
  __shared__ float sW2[32];
  __shared__ float sW3[3*DD*DD];
  __shared__ u32   smsg[256*10];
  __shared__ int   sdst[256];
  __shared__ int   s_prevdst, s_nextdst;
  if (HASH){
    for (int t=threadIdx.x; t<HID*DD; t+=blockDim.x){ int j=t/DD,k=t-j*DD; sW1h[t]=w1[j*3*DD+k]; }
    for (int t=threadIdx.x; t<3*DD*DD; t+=blockDim.x) sW3[t]=W3[t];
  }
  if (threadIdx.x<HID) sW2[threadIdx.x]=w2[threadIdx.x];

  int tid = threadIdx.x;
  int bsize = E - bstart; if (bsize>256) bsize=256;
  int j = bstart + tid;
  bool active = (tid < bsize);

  if (tid==0){
    s_prevdst = (bstart>0) ? recs[-1 + (ptrdiff_t)bstart].w : -1;
    s_nextdst = (bstart+bsize < E) ? recs[bstart+bsize].w : -1;
  }
  __syncthreads();   // weights + s_prev/s_next visible

  int dstv = -1;
  float m[DD];
  if (active){
    int4 rc = recs[j];
    int s = rc.x;
    int r = rc.y & 0xFFFF;
    int q = ((unsigned)rc.y) >> 16;
    int t = rc.z;
    dstv  = rc.w;
    int sel = (t>0)?2:((t==0)?1:0);
    int ta = (t<0)?-t:t;

    float h[DD];
    if (HASH){
      const uint4* hp=(const uint4*)(hin+(size_t)s*HROW);   // 64 B aligned, 1 cacheline
      uint4 A=hp[0], B=hp[1]; uint2 Cc=*((const uint2*)(hp+2));
      h[0]=__uint_as_float(A.x<<16);  h[1]=__uint_as_float(A.x&0xFFFF0000u);
      h[2]=__uint_as_float(A.y<<16);  h[3]=__uint_as_float(A.y&0xFFFF0000u);
      h[4]=__uint_as_float(A.z<<16);  h[5]=__uint_as_float(A.z&0xFFFF0000u);
      h[6]=__uint_as_float(A.w<<16);  h[7]=__uint_as_float(A.w&0xFFFF0000u);
      h[8]=__uint_as_float(B.x<<16);  h[9]=__uint_as_float(B.x&0xFFFF0000u);
      h[10]=__uint_as_float(B.y<<16); h[11]=__uint_as_float(B.y&0xFFFF0000u);
      h[12]=__uint_as_float(B.z<<16); h[13]=__uint_as_float(B.z&0xFFFF0000u);
      h[14]=__uint_as_float(B.w<<16); h[15]=__uint_as_float(B.w&0xFFFF0000u);
      h[16]=__uint_as_float(Cc.x<<16);h[17]=__uint_as_float(Cc.x&0xFFFF0000u);
      h[18]=__uint_as_float(Cc.y<<16);h[19]=__uint_as_float(Cc.y&0xFFFF0000u);
      // leaky already applied at store time
    }

    // attention: z streamed chunk-wise against LDS weights (no a[30])
    float z=0.f;
    {
      const float4* ap=(const float4*)(AR+(size_t)r*32);
      const float4* qp=(const float4*)(AQ+(size_t)q*32);
#pragma unroll
      for (int c=0;c<7;c++){
        float4 x=ap[c], y=qp[c];
        float s4[4]={x.x+y.x, x.y+y.y, x.z+y.z, x.w+y.w};
#pragma unroll
        for (int u=0;u<4;u++){
          int jj=4*c+u;
          if (HASH){
            const float4* wr=(const float4*)&sW1h[jj*DD];
            float sum=s4[u];
#pragma unroll
            for (int c2=0;c2<5;c2++){ float4 w=wr[c2]; sum += h[4*c2]*w.x+h[4*c2+1]*w.y+h[4*c2+2]*w.z+h[4*c2+3]*w.w; }
            s4[u]=sum;
          }
          z += fmaxf(s4[u],0.f)*sW2[jj];
        }
      }
      float2 x2=*(const float2*)(AR+(size_t)r*32+28);
      float2 y2=*(const float2*)(AQ+(size_t)q*32+28);
      float s0=x2.x+y2.x, s1=x2.y+y2.y;
      if (HASH){
        const float4* wr0=(const float4*)&sW1h[28*DD];
        const float4* wr1=(const float4*)&sW1h[29*DD];
#pragma unroll
        for (int c2=0;c2<5;c2++){
          float4 wA=wr0[c2], wB=wr1[c2];
          s0 += h[4*c2]*wA.x+h[4*c2+1]*wA.y+h[4*c2+2]*wA.z+h[4*c2+3]*wA.w;
          s1 += h[4*c2]*wB.x+h[4*c2+1]*wB.y+h[4*c2+2]*wB.z+h[4*c2+3]*wB.w;
        }
      }
      z += fmaxf(s0,0.f)*sW2[28] + fmaxf(s1,0.f)*sW2[29];
    }
    float score = 1.f/(1.f+__expf(-z));

    // transform: bf16 RT row (1 line) + optional h @ Wsel (LDS), streamed per chunk
    size_t rowid=((size_t)(sel*nrel+r)*ntime + ta);
    const uint4* tp=(const uint4*)(RTb + rowid*16);
    uint4 TA=tp[0], TB=tp[1]; uint2 TC=*((const uint2*)(tp+2));
    u32 tw[10]={TA.x,TA.y,TA.z,TA.w,TB.x,TB.y,TB.z,TB.w,TC.x,TC.y};
#pragma unroll
    for (int c=0;c<5;c++){
      float mv[4];
      mv[0]=__uint_as_float(tw[2*c]<<16);   mv[1]=__uint_as_float(tw[2*c]&0xFFFF0000u);
      mv[2]=__uint_as_float(tw[2*c+1]<<16); mv[3]=__uint_as_float(tw[2*c+1]&0xFFFF0000u);
      if (HASH){
#pragma unroll
        for (int u=0;u<4;u++){
          const float4* wr=(const float4*)&sW3[sel*DD*DD+(4*c+u)*DD];
          float sum=mv[u];
#pragma unroll
          for (int c2=0;c2<5;c2++){ float4 w=wr[c2]; sum += h[4*c2]*w.x+h[4*c2+1]*w.y+h[4*c2+2]*w.z+h[4*c2+3]*w.w; }
          mv[u]=sum;
        }
      }
#pragma unroll
      for (int u=0;u<4;u++) m[4*c+u]=score*mv[u];
    }
#pragma unroll
    for (int i2=0;i2<10;i2++) smsg[tid*10+i2]=pkbf(m[2*i2],m[2*i2+1]);
  }
  sdst[tid] = active ? dstv : -2;
  __syncthreads();

  if (!active) return;
  bool isHead = (tid==0) ? (s_prevdst != dstv) : (sdst[tid-1] != dstv);
  if (!(isHead || tid==0)) return;
  int k=tid+1;
  for (; k<bsize && sdst[k]==dstv; ++k){
    const u32* row=&smsg[k*10];
#pragma unroll
    for (int i2=0;i2<10;i2++){
      u32 w=row[i2];
      m[2*i2]  +=__uint_as_float(w<<16);
      m[2*i2+1]+=__uint_as_float(w&0xFFFF0000u);
    }
  }
  bool crossStart = (tid==0 && !isHead);
  bool crossEnd   = (k==bsize) && (s_nextdst==dstv);
  if (crossStart || crossEnd){
    float* o = bufF + (size_t)dstv*DD;
#pragma unroll
    for (int i=0;i<DD;i++) atomicAdd(o+i, m[i]);
    if (isHead){                          // one list entry per crossing segment
      int p = atomicAdd(listc,1);
      list[p] = dstv;
    }
  } else {
    if (!FINAL){
      u32 o10[10];
#pragma unroll
      for (int i2=0;i2<10;i2++){
        float x0=m[2*i2], x1=m[2*i2+1];
        x0=fmaxf(x0,0.01f*x0); x1=fmaxf(x1,0.01f*x1);     // leaky at store
        o10[i2]=pkbf(x0,x1);
      }
      uint4* hp=(uint4*)(hout+(size_t)dstv*HROW);
      hp[0]=make_uint4(o10[0],o10[1],o10[2],o10[3]);
      hp[1]=make_uint4(o10[4],o10[5],o10[6],o10[7]);
      *((uint2*)(hp+2))=make_uint2(o10[8],o10[9]);
    } else {
      float rsum=bcls[0];
#pragma unroll
      for (int i=0;i<DD;i++){ float x=fmaxf(m[i],0.01f*m[i]); rsum += x*wcls[i]; }
      long long stride = nentp[0];
      outp[(long long)nbv[dstv]*stride + nev[dstv]] = rsum;
    }
  }
}

// ---- finish crossing segments: read f32 spill, re-zero it, emit bf16 row (or final score) ----
template<bool FINAL>
__global__ void __launch_bounds__(256) k_fixup(float* __restrict__ bufF, u16* __restrict__ hout,
   const float* __restrict__ wcls,const float* __restrict__ bcls,
   const int* __restrict__ nb,const int* __restrict__ ne,const int* __restrict__ nentp,
   float* __restrict__ out,const int* __restrict__ list,const int* __restrict__ listc){
  int c=*listc;
  for (int i=blockIdx.x*blockDim.x+threadIdx.x; i<c; i+=gridDim.x*blockDim.x){
    int n=list[i];
    float* p=bufF+(size_t)n*DD;
    float v[DD];
#pragma unroll
    for (int jj=0;jj<DD;jj++){ v[jj]=p[jj]; p[jj]=0.f; }
    if (FINAL){
      float rsum=bcls[0];
#pragma unroll
      for (int jj=0;jj<DD;jj++){ float x=fmaxf(v[jj],0.01f*v[jj]); rsum+=x*wcls[jj]; }
      long long stride=nentp[0];
      out[(long long)nb[n]*stride+ne[n]]=rsum;
    } else {
      u32 o10[10];
#pragma unroll
      for (int i2=0;i2<10;i2++){
        float x0=v[2*i2], x1=v[2*i2+1];
        x0=fmaxf(x0,0.01f*x0); x1=fmaxf(x1,0.01f*x1);
        o10[i2]=pkbf(x0,x1);
      }
      uint4* hp=(uint4*)(hout+(size_t)n*HROW);
      hp[0]=make_uint4(o10[0],o10[1],o10[2],o10[3]);
      hp[1]=make_uint4(o10[4],o10[5],o10[6],o10[7]);
      *((uint2*)(hp+2))=make_uint2(o10[8],o10[9]);
    }
  }
}

// ================= fallback (round-2 proven atomic path, f32) =================
template<bool HASH>
__global__ void __launch_bounds__(256) k_edge(
    const int* __restrict__ src, const int* __restrict__ dst,
    const int* __restrict__ rel, const int* __restrict__ qrel,
    const int* __restrict__ rtm,
    const float* __restrict__ hin, float* __restrict__ hout,
    const float* __restrict__ RT, const float* __restrict__ AR, const float* __restrict__ AQ,
    const float* __restrict__ w1, const float* __restrict__ w2, const float* __restrict__ W3,
    int E, int nrel, int ntime)
{
  __shared__ float sW1h[HID*DD];
  __shared__ float sW2[32];
  __shared__ float sW3[3*DD*DD];
  for (int t=threadIdx.x; t<HID*DD; t+=blockDim.x){ int j=t/DD,k=t-j*DD; sW1h[t]=w1[j*3*DD+k]; }
  if (threadIdx.x<HID) sW2[threadIdx.x]=w2[threadIdx.x];
  for (int t=threadIdx.x; t<3*DD*DD; t+=blockDim.x) sW3[t]=W3[t];
  __syncthreads();
  int e = blockIdx.x*blockDim.x+threadIdx.x;
  if (e>=E) return;
  int s=src[e], d=dst[e], r=rel[e], q=qrel[e], t=rtm[e];
  int sel = (t>0)?2:((t==0)?1:0);
  int ta = (t<0)?-t:t;
  float h[DD];
  if (HASH){
    load20(hin+(size_t)s*DD, h);
#pragma unroll
    for (int i=0;i<DD;i++) h[i]=fmaxf(h[i],0.01f*h[i]);
  }
  float a[HID];
  {
    const float4* ap=(const float4*)(AR+(size_t)r*32);
    const float4* qp=(const float4*)(AQ+(size_t)q*32);
#pragma unroll
    for (int c=0;c<7;c++){
      float4 x=ap[c], y=qp[c];
      a[4*c+0]=x.x+y.x; a[4*c+1]=x.y+y.y; a[4*c+2]=x.z+y.z; a[4*c+3]=x.w+y.w;
    }
    float2 x=*(const float2*)(AR+(size_t)r*32+28);
    float2 y=*(const float2*)(AQ+(size_t)q*32+28);
    a[28]=x.x+y.x; a[29]=x.y+y.y;
  }
  if (HASH){
#pragma unroll
    for (int j=0;j<HID;j++){
      const float4* wr=(const float4*)&sW1h[j*DD];
      float sum=a[j];
#pragma unroll
      for (int c=0;c<5;c++){ float4 w=wr[c]; sum += h[4*c]*w.x+h[4*c+1]*w.y+h[4*c+2]*w.z+h[4*c+3]*w.w; }
      a[j]=sum;
    }
  }
  float z=0.f;
#pragma unroll
  for (int j=0;j<HID;j++) z += fmaxf(a[j],0.f)*sW2[j];
  float score = 1.f/(1.f+__expf(-z));
  float tr[DD];
  load20(RT + ((size_t)(sel*nrel+r)*ntime + ta)*DD, tr);
  if (HASH){
    const float* Ws = sW3 + sel*DD*DD;
#pragma unroll
    for (int i=0;i<DD;i++){
      const float4* wr=(const float4*)(Ws+i*DD);
      float sum=tr[i];
#pragma unroll
      for (int c=0;c<5;c++){ float4 w=wr[c]; sum += h[4*c]*w.x+h[4*c+1]*w.y+h[4*c+2]*w.z+h[4*c+3]*w.w; }
      tr[i]=sum;
    }
  }
  float* o = hout + (size_t)d*DD;
#pragma unroll
  for (int i=0;i<DD;i++) atomicAdd(o+i, score*tr[i]);
}

__global__ void k_result(const float* __restrict__ h, const float* __restrict__ wcls,
                         const float* __restrict__ bcls, float* __restrict__ res, int N){
  int i = blockIdx.x*blockDim.x+threadIdx.x;
  if (i>=N) return;
  float acc = bcls[0];
  const float4* q=(const float4*)(h+(size_t)i*DD);
#pragma unroll
  for (int c=0;c<5;c++){
    float4 v=q[c];
    float x0=fmaxf(v.x,0.01f*v.x), x1=fmaxf(v.y,0.01f*v.y);
    float x2=fmaxf(v.z,0.01f*v.z), x3=fmaxf(v.w,0.01f*v.w);
    acc += x0*wcls[4*c]+x1*wcls[4*c+1]+x2*wcls[4*c+2]+x3*wcls[4*c+3];
  }
  res[i]=acc;
}

__global__ void k_scatter(const float* __restrict__ res, const int* __restrict__ nb,
                          const int* __restrict__ ne, const int* __restrict__ nentp,
                          float* __restrict__ out, int N){
  int i=blockIdx.x*blockDim.x+threadIdx.x;
  if (i>=N) return;
  long long stride = nentp[0];
  out[(long long)nb[i]*stride + ne[i]] = res[i];
}

extern "C" void kernel_launch(void* const* d_in, const int* in_sizes, int n_in,
                              void* d_out, int out_size, void* d_ws, size_t ws_size,
                              hipStream_t stream){
  const int*   src =(const int*)d_in[0];
  const int*   dst =(const int*)d_in[1];
  const int*   rel =(const int*)d_in[2];
  const int*   qrel=(const int*)d_in[3];
  const int*   rtm =(const int*)d_in[4];
  const int*   nb  =(const int*)d_in[5];
  const int*   ne  =(const int*)d_in[6];
  const float* rela=(const float*)d_in[7];
  const float* timee=(const float*)d_in[8];
  const float* w1  =(const float*)d_in[9];
  const float* w2  =(const float*)d_in[10];
  const float* wp  =(const float*)d_in[11];
  const float* wn  =(const float*)d_in[12];
  const float* wf  =(const float*)d_in[13];
  const float* wcls=(const float*)d_in[14];
  const float* bcls=(const float*)d_in[15];
  const int*   nentp=(const int*)d_in[17];

  const int Lc=3;
  int LE=in_sizes[0]; int E=LE/Lc;
  int N=in_sizes[5];
  int nrel=in_sizes[7]/DD;
  int ntime=in_sizes[8]/DD;

  auto al=[](size_t x){ return (x+(size_t)255)&~(size_t)255; };
  size_t szBufB=al((size_t)N*HROW*2);              // bf16 hidden, 64 B rows
  size_t szBufF=al((size_t)N*DD*4);                // f32 crossing spill
  size_t szBuf =al((size_t)N*DD*4);                // fallback f32 bufs
  size_t szRTb =al((size_t)3*nrel*ntime*64);       // packed bf16 RT, 64 B rows
  size_t szRTf =al((size_t)3*nrel*ntime*DD*4);     // fallback f32 RT
  size_t szA   =al((size_t)nrel*32*4);
  size_t szW3  =al((size_t)3*DD*DD*4);
  size_t szRow =al((size_t)Lc*((size_t)N+1)*4);
  size_t szRank=al((size_t)LE*4);
  size_t szCnt =al((size_t)Lc*N*4);
  size_t szRecs=al((size_t)LE*16);
  size_t szPart=al((size_t)NB_SCAN*4);
  size_t szList=al((size_t)(131072+16)*4);
  size_t need = 2*szBufB+szBufF+szRTb+2*szA+szW3+szRow+szRank+szCnt+szRecs+szPart+szList;

  dim3 blk(256);
  int prepTot = (3*DD*DD > nrel*HID) ? 3*DD*DD : nrel*HID;
  int rtTot=3*nrel*ntime;

  if (ws_size >= need){
    char* base=(char*)d_ws;
    size_t off=0;
    u16*   b0 =(u16*)(base+off);   off+=szBufB;
    u16*   b1 =(u16*)(base+off);   off+=szBufB;
    float* bufF=(float*)(base+off); off+=szBufF;
    u32*   RTb =(u32*)(base+off);  off+=szRTb;
    float* AR  =(float*)(base+off); off+=szA;
    float* AQ  =(float*)(base+off); off+=szA;
    float* W3  =(float*)(base+off); off+=szW3;
    int*   rowptr=(int*)(base+off); off+=szRow;     // Lc*(N+1)
    int*   rank=(int*)(base+off);  off+=szRank;
    int*   cnt =(int*)(base+off);  off+=szCnt;      // Lc*N
    int4*  recs=(int4*)(base+off); off+=szRecs;
    int*   part=(int*)(base+off);  off+=szPart;
    int*   listc=(int*)(base+off);
    int*   list =listc+16;          off+=szList;

    float* dout=(float*)d_out;

    (void)hipMemsetAsync(cnt,0,(size_t)Lc*N*4,stream);
    k_prep<<<dim3((prepTot+255)/256),blk,0,stream>>>(rela,w1,wp,wn,wf,W3,AR,AQ,nrel);
    k_rtb<<<dim3((rtTot+255)/256),blk,0,stream>>>(rela,timee,W3,RTb,nrel,ntime);

    size_t nd4=(size_t)out_size>>2;
    size_t nbB4=(size_t)N*HROW*2/16;     // uint4 count per bf16 buf
    size_t nf4=(size_t)N*DD/4;
    k_pre<<<dim3(8192),blk,0,stream>>>(dst,cnt,rank,E,(float4*)dout,nd4,
                                       (uint4*)b0,(uint4*)b1,nbB4,(float4*)bufF,nf4);

    int C=(N+NB_SCAN-1)/NB_SCAN;
    int LB=(E+255)/256;
    int H=(LB+1)/2;

    for (int l=0;l<Lc;++l){
      int* cnt_l = cnt + (size_t)l*N;
      int* row_l = rowptr + (size_t)l*(N+1);
      k_scan_part<<<dim3(NB_SCAN),blk,0,stream>>>(cnt_l,part,N,C);
      k_scan_top<<<dim3(1),dim3(NB_SCAN),0,stream>>>(part,listc);
      k_scan_write<<<dim3(NB_SCAN),blk,0,stream>>>(cnt_l,part,row_l,N,C);
      size_t eo=(size_t)l*E;
      int xb = (l==0)?1024:0;
      k_scat<<<dim3(xb+LB),blk,0,stream>>>(src+eo,dst+eo,rel+eo,qrel+eo,rtm+eo,
          rank+eo,row_l,recs+eo,E,xb,dout,nb,ne,nentp,bcls,N);
      if (l==0){
        k_fused<false,true,false><<<dim3(3*H),blk,0,stream>>>(recs,nullptr,b0,bufF,
            RTb,AR,AQ,w1,w2,W3,E,nrel,ntime,
            dst+(size_t)E,cnt+(size_t)N,rank+(size_t)E,E,
            nullptr,nullptr,nullptr,nullptr,nullptr,nullptr,list,listc);
        k_fixup<false><<<dim3(128),blk,0,stream>>>(bufF,b0,wcls,bcls,nb,ne,nentp,dout,list,listc);
      } else if (l==1){
        k_fused<true,true,false><<<dim3(3*H),blk,0,stream>>>(recs+(size_t)E,b0,b1,bufF,
            RTb,AR,AQ,w1,w2,W3,E,nrel,ntime,
            dst+(size_t)2*E,cnt+(size_t)2*N,rank+(size_t)2*E,E,
            nullptr,nullptr,nullptr,nullptr,nullptr,nullptr,list,listc);
        k_fixup<false><<<dim3(128),blk,0,stream>>>(bufF,b1,wcls,bcls,nb,ne,nentp,dout,list,listc);
      } else {
        k_fused<true,false,true><<<dim3(LB),blk,0,stream>>>(recs+(size_t)2*E,b1,nullptr,bufF,
            RTb,AR,AQ,w1,w2,W3,E,nrel,ntime,
            nullptr,nullptr,nullptr,0,
            wcls,bcls,nb,ne,nentp,dout,list,listc);
        k_fixup<true><<<dim3(128),blk,0,stream>>>(bufF,nullptr,wcls,bcls,nb,ne,nentp,dout,list,listc);
      }
    }
  } else {
    // fallback: proven round-2 atomic path (scratch carved from d_out, res in ws)
    char* base=(char*)d_out; float* res=(float*)d_ws;
    size_t off=0;
    float* buf0=(float*)(base+off); off+=szBuf;
    float* buf1=(float*)(base+off); off+=szBuf;
    float* RT  =(float*)(base+off); off+=szRTf;
    float* AR  =(float*)(base+off); off+=szA;
    float* AQ  =(float*)(base+off); off+=szA;
    float* W3  =(float*)(base+off); off+=szW3;
    k_prep<<<dim3((prepTot+255)/256),blk,0,stream>>>(rela,w1,wp,wn,wf,W3,AR,AQ,nrel);
    k_rt<<<dim3((rtTot+255)/256),blk,0,stream>>>(rela,timee,W3,RT,nrel,ntime);
    dim3 egrid((E+255)/256);
    dim3 ngrid((N+255)/256);
    (void)hipMemsetAsync(buf0,0,(size_t)N*DD*4,stream);
    k_edge<false><<<egrid,blk,0,stream>>>(src,dst,rel,qrel,rtm,nullptr,buf0,RT,AR,AQ,w1,w2,W3,E,nrel,ntime);
    (void)hipMemsetAsync(buf1,0,(size_t)N*DD*4,stream);
    k_edge<true><<<egrid,blk,0,stream>>>(src+(size_t)E,dst+(size_t)E,rel+(size_t)E,qrel+(size_t)E,rtm+(size_t)E,
                                         buf0,buf1,RT,AR,AQ,w1,w2,W3,E,nrel,ntime);
    (void)hipMemsetAsync(buf0,0,(size_t)N*DD*4,stream);
    k_edge<true><<<egrid,blk,0,stream>>>(src+(size_t)2*E,dst+(size_t)2*E,rel+(size_t)2*E,qrel+(size_t)2*E,rtm+(size_t)2*E,
                                         buf1,buf0,RT,AR,AQ,w1,w2,W3,E,nrel,ntime);
    k_result<<<ngrid,blk,0,stream>>>(buf0,wcls,bcls,res,N);
    (void)hipMemsetAsync(d_out,0,(size_t)out_size*sizeof(float),stream);
    k_scatter<<<ngrid,blk,0,stream>>>(res,nb,ne,nentp,(float*)d_out,N);
  }
}

// Round 10
// 1057.324 us; speedup vs baseline: 2.6606x; 1.0261x over previous
//
#include <hip/hip_runtime.h>
#include <hip/hip_bf16.h>
#include <cstdint>

#define DD 20
#define HID 30
#define NB_SCAN 1024
#define HROW 32   // bf16 hidden row stride (64 B, one cacheline)

typedef unsigned int  u32;
typedef unsigned short u16;

__device__ __forceinline__ void load20(const float* __restrict__ p, float* r){
  const float4* q = (const float4*)p;
#pragma unroll
  for (int i=0;i<5;i++){ float4 v=q[i]; r[4*i+0]=v.x; r[4*i+1]=v.y; r[4*i+2]=v.z; r[4*i+3]=v.w; }
}

__device__ __forceinline__ u32 pkbf(float a, float b){
  u32 ua=__float_as_uint(a); ua=(ua+0x7FFFu+((ua>>16)&1u))>>16;
  u32 ub=__float_as_uint(b); ub=(ub+0x7FFFu+((ub>>16)&1u))>>16;
  return ua | (ub<<16);
}

__global__ void k_prep(const float* __restrict__ rela, const float* __restrict__ w1,
                       const float* __restrict__ wp, const float* __restrict__ wn,
                       const float* __restrict__ wf,
                       float* __restrict__ W3, float* __restrict__ AR, float* __restrict__ AQ,
                       int nrel){
  int t = blockIdx.x*blockDim.x + threadIdx.x;
  if (t < 3*DD*DD){
    int s = t/(DD*DD), idx = t%(DD*DD);
    W3[t] = (s==0)?wp[idx]:((s==1)?wn[idx]:wf[idx]);
  }
  if (t < nrel*HID){
    int r=t/HID, j=t-r*HID;
    float sr=0.f, sq=0.f;
#pragma unroll
    for (int k=0;k<DD;k++){
      float e = rela[r*DD+k];
      sr += e*w1[j*3*DD + DD + k];
      sq += e*w1[j*3*DD + 2*DD + k];
    }
    AR[r*32+j]=sr; AQ[r*32+j]=sq;
  }
}

// RW[(sel*nrel+r)*20+i] = rela[r] . W3[sel][i][:]   (48 KB)
// TW[(sel*ntime+t)*20+i] = time[t] . W3[sel][i][:]  (88 KB)
__global__ void k_rwtw(const float* __restrict__ rela, const float* __restrict__ timee,
                       const float* __restrict__ W3,
                       float* __restrict__ RW, float* __restrict__ TW,
                       int nrel, int ntime){
  int t = blockIdx.x*blockDim.x+threadIdx.x;
  int totR = 3*nrel*DD, totT = 3*ntime*DD;
  if (t < totR){
    int sel = t/(nrel*DD); int rem = t - sel*nrel*DD; int r = rem/DD; int i = rem - r*DD;
    const float* w = W3 + sel*DD*DD + i*DD;
    const float* e = rela + (size_t)r*DD;
    float s=0.f;
#pragma unroll
    for (int k=0;k<DD;k++) s += e[k]*w[k];
    RW[t]=s;
  }
  if (t < totT){
    int sel = t/(ntime*DD); int rem = t - sel*ntime*DD; int tt = rem/DD; int i = rem - tt*DD;
    const float* w = W3 + sel*DD*DD + i*DD;
    const float* e = timee + (size_t)tt*DD;
    float s=0.f;
#pragma unroll
    for (int k=0;k<DD;k++) s += e[k]*w[k];
    TW[t]=s;
  }
}

// f32 RT (fallback path only)
__global__ void k_rt(const float* __restrict__ rela, const float* __restrict__ timee,
                     const float* __restrict__ W3, float* __restrict__ RT,
                     int nrel, int ntime){
  int row = blockIdx.x*blockDim.x+threadIdx.x;
  int tot = 3*nrel*ntime;
  if (row>=tot) return;
  int per = nrel*ntime;
  int sel = row/per; int rem = row - sel*per; int r = rem/ntime; int t = rem - r*ntime;
  float e[DD], tv[DD];
  load20(rela + (size_t)r*DD, e);
  load20(timee + (size_t)t*DD, tv);
#pragma unroll
  for (int k=0;k<DD;k++) e[k]+=tv[k];
  const float* W = W3 + sel*DD*DD;
  float o[DD];
#pragma unroll
  for (int i=0;i<DD;i++){
    const float4* wr = (const float4*)(W + i*DD);
    float s=0.f;
#pragma unroll
    for (int c=0;c<5;c++){ float4 w=wr[c]; s += e[4*c]*w.x + e[4*c+1]*w.y + e[4*c+2]*w.z + e[4*c+3]*w.w; }
    o[i]=s;
  }
  float4* op=(float4*)(RT + (size_t)row*DD);
#pragma unroll
  for (int c=0;c<5;c++){ float4 v; v.x=o[4*c]; v.y=o[4*c+1]; v.z=o[4*c+2]; v.w=o[4*c+3]; op[c]=v; }
}

// ---- F0: zero d_out / bf16 bufs / f32 spill buf (even blocks) || layer-0 histogram (odd) ----
__global__ void __launch_bounds__(256) k_pre(const int* __restrict__ dst0, int* __restrict__ cnt0,
        int* __restrict__ rank0, int E,
        float4* __restrict__ dout4, size_t nd4,
        uint4* __restrict__ b0, uint4* __restrict__ b1, size_t nbB4,
        float4* __restrict__ bF, size_t nf4){
  int g=blockIdx.x, tid=threadIdx.x;
  int half=gridDim.x>>1;
  if (g & 1){
    int stride=half*256;
    for (int e=(g>>1)*256+tid; e<E; e+=stride)
      rank0[e]=atomicAdd(&cnt0[dst0[e]],1);
  } else {
    float4 z=make_float4(0.f,0.f,0.f,0.f);
    uint4 zu=make_uint4(0u,0u,0u,0u);
    size_t i=(size_t)(g>>1)*256+tid, st=(size_t)half*256;
    for (size_t k=i;k<nd4;k+=st) dout4[k]=z;
    for (size_t k=i;k<nbB4;k+=st){ b0[k]=zu; b1[k]=zu; }
    for (size_t k=i;k<nf4;k+=st) bF[k]=z;
  }
}

// ---- per-layer scan (N elements) ----
__global__ void k_scan_part(const int* __restrict__ cnt, int* __restrict__ part, int M, int C){
  __shared__ int sm[256];
  int b=blockIdx.x, t=threadIdx.x;
  int lo=b*C, hi=lo+C; if (hi>M) hi=M; if (lo>M) lo=M;
  int s=0;
  for (int i=lo+t; i<hi; i+=256) s+=cnt[i];
  sm[t]=s; __syncthreads();
  for (int o=128;o>0;o>>=1){ if (t<o) sm[t]+=sm[t+o]; __syncthreads(); }
  if (t==0) part[b]=sm[0];
}

__global__ void k_scan_top(int* __restrict__ part, int* __restrict__ listc){
  __shared__ int sm[NB_SCAN];
  int t=threadIdx.x;
  if (t==0) *listc=0;
  int v=part[t]; sm[t]=v; __syncthreads();
  for (int o=1;o<NB_SCAN;o<<=1){
    int u=(t>=o)?sm[t-o]:0; __syncthreads();
    sm[t]+=u; __syncthreads();
  }
  part[t]=sm[t]-v;   // exclusive
}

__global__ void k_scan_write(const int* __restrict__ cnt, const int* __restrict__ part,
                             int* __restrict__ rowptr, int M, int C){
  __shared__ int sm[256];
  int b=blockIdx.x, t=threadIdx.x;
  int lo=b*C, hi=lo+C; if (hi>M) hi=M; if (lo>M) lo=M;
  int run=part[b];
  for (int base=lo; base<hi; base+=256){
    int i=base+t;
    int v=(i<hi)?cnt[i]:0;
    sm[t]=v; __syncthreads();
    for (int o=1;o<256;o<<=1){
      int u=(t>=o)?sm[t-o]:0; __syncthreads();
      sm[t]+=u; __syncthreads();
    }
    if (i<hi) rowptr[i]=run+sm[t]-v;
    int tot=sm[255];
    __syncthreads();
    run+=tot;
  }
  if (hi==M && t==0) rowptr[M]=run;
}

// ---- per-layer scatter to CSR slots; l0 extra blocks fill b_cls into all node output slots ----
__global__ void __launch_bounds__(256) k_scat(const int* __restrict__ src,const int* __restrict__ dst,
  const int* __restrict__ rel,const int* __restrict__ qrel,const int* __restrict__ rtm,
  const int* __restrict__ rank,const int* __restrict__ rowptr,int4* __restrict__ recs,int E,
  int xb,
  float* __restrict__ dout,const int* __restrict__ nb,const int* __restrict__ ne,
  const int* __restrict__ nentp,const float* __restrict__ bcls,int N){
  int g=blockIdx.x, tid=threadIdx.x;
  if (g<xb){
    float b=bcls[0]; long long stride=nentp[0];
    for (int n=g*256+tid;n<N;n+=xb*256) dout[(long long)nb[n]*stride+ne[n]]=b;
    return;
  }
  int e=(g-xb)*256+tid;
  if (e>=E) return;
  int d=dst[e];
  int pos=rowptr[d]+rank[e];
  recs[pos]=make_int4(src[e], rel[e]|(qrel[e]<<16), rtm[e], d);
}

// ---- fused layer: per-edge compute + LDS(bf16) segmented reduce, bf16 hidden + RW/TW split RT,
//      optionally ∥ next-layer hist, optionally fused final epilogue ----
template<bool HASH,bool HIST,bool FINAL>
__global__ void __launch_bounds__(256) k_fused(
    const int4* __restrict__ recs,
    const u16* __restrict__ hin, u16* __restrict__ hout, float* __restrict__ bufF,
    const float* __restrict__ RW, const float* __restrict__ TW,
    const float* __restrict__ AR, const float* __restrict__ AQ,
    const float* __restrict__ w1, const float* __restrict__ w2, const float* __restrict__ W3,
    int E, int nrel, int ntime,
    const int* __restrict__ ndst, int* __restrict__ ncnt, int* __restrict__ nrank, int nE,
    const float* __restrict__ wcls, const float* __restrict__ bcls,
    const int* __restrict__ nbv, const int* __restrict__ nev, const int* __restrict__ nentp,
    float* __restrict__ outp, int* __restrict__ list, int* __restrict__ listc)
{
  int lb;
  if (HIST){
    int g=blockIdx.x;
    int r3=g%3, b3=g/3;
    if (r3==2){                           // histogram role (next layer)
      int H=gridDim.x/3;
      int stride=H*256;
      for (int e=b3*256+threadIdx.x; e<nE; e+=stride)
        nrank[e]=atomicAdd(&ncnt[ndst[e]],1);
      return;
    }
    lb=b3*2+r3;
  } else lb=blockIdx.x;
  int bstart=lb*256;
  if (bstart>=E) return;

  __shared__ float sW1h[HID*DD];
  __shared__ float sW2[32];
  __shared__ float sW3[3*DD*DD];
  __shared__ u32   smsg[256*10];
  __shared__ int   sdst[256];
  __shared__ int   s_prevdst, s_nextdst;
  if (HASH){
    for (int t=threadIdx.x; t<HID*DD; t+=blockDim.x){ int j=t/DD,k=t-j*DD; sW1h[t]=w1[j*3*DD+k]; }
    for (int t=threadIdx.x; t<3*DD*DD; t+=blockDim.x) sW3[t]=W3[t];
  }
  if (threadIdx.x<HID) sW2[threadIdx.x]=w2[threadIdx.x];

  int tid = threadIdx.x;
  int bsize = E - bstart; if (bsize>256) bsize=256;
  int j = bstart + tid;
  bool active = (tid < bsize);

  if (tid==0){
    s_prevdst = (bstart>0) ? recs[-1 + (ptrdiff_t)bstart].w : -1;
    s_nextdst = (bstart+bsize < E) ? recs[bstart+bsize].w : -1;
  }
  __syncthreads();   // weights + s_prev/s_next visible

  int dstv = -1;
  float m[DD];
  if (active){
    int4 rc = recs[j];
    int s = rc.x;
    int r = rc.y & 0xFFFF;
    int q = ((unsigned)rc.y) >> 16;
    int t = rc.z;
    dstv  = rc.w;
    int sel = (t>0)?2:((t==0)?1:0);
    int ta = (t<0)?-t:t;

    float h[DD];
    if (HASH){
      const uint4* hp=(const uint4*)(hin+(size_t)s*HROW);   // 64 B aligned, 1 cacheline
      uint4 A=hp[0], B=hp[1]; uint2 Cc=*((const uint2*)(hp+2));
      h[0]=__uint_as_float(A.x<<16);  h[1]=__uint_as_float(A.x&0xFFFF0000u);
      h[2]=__uint_as_float(A.y<<16);  h[3]=__uint_as_float(A.y&0xFFFF0000u);
      h[4]=__uint_as_float(A.z<<16);  h[5]=__uint_as_float(A.z&0xFFFF0000u);
      h[6]=__uint_as_float(A.w<<16);  h[7]=__uint_as_float(A.w&0xFFFF0000u);
      h[8]=__uint_as_float(B.x<<16);  h[9]=__uint_as_float(B.x&0xFFFF0000u);
      h[10]=__uint_as_float(B.y<<16); h[11]=__uint_as_float(B.y&0xFFFF0000u);
      h[12]=__uint_as_float(B.z<<16); h[13]=__uint_as_float(B.z&0xFFFF0000u);
      h[14]=__uint_as_float(B.w<<16); h[15]=__uint_as_float(B.w&0xFFFF0000u);
      h[16]=__uint_as_float(Cc.x<<16);h[17]=__uint_as_float(Cc.x&0xFFFF0000u);
      h[18]=__uint_as_float(Cc.y<<16);h[19]=__uint_as_float(Cc.y&0xFFFF0000u);
      // leaky already applied at store time
    }

    // attention: z streamed chunk-wise against LDS weights (no a[30])
    float z=0.f;
    {
      const float4* ap=(const float4*)(AR+(size_t)r*32);
      const float4* qp=(const float4*)(AQ+(size_t)q*32);
#pragma unroll
      for (int c=0;c<7;c++){
        float4 x=ap[c], y=qp[c];
        float s4[4]={x.x+y.x, x.y+y.y, x.z+y.z, x.w+y.w};
#pragma unroll
        for (int u=0;u<4;u++){
          int jj=4*c+u;
          if (HASH){
            const float4* wr=(const float4*)&sW1h[jj*DD];
            float sum=s4[u];
#pragma unroll
            for (int c2=0;c2<5;c2++){ float4 w=wr[c2]; sum += h[4*c2]*w.x+h[4*c2+1]*w.y+h[4*c2+2]*w.z+h[4*c2+3]*w.w; }
            s4[u]=sum;
          }
          z += fmaxf(s4[u],0.f)*sW2[jj];
        }
      }
      float2 x2=*(const float2*)(AR+(size_t)r*32+28);
      float2 y2=*(const float2*)(AQ+(size_t)q*32+28);
      float s0=x2.x+y2.x, s1=x2.y+y2.y;
      if (HASH){
        const float4* wr0=(const float4*)&sW1h[28*DD];
        const float4* wr1=(const float4*)&sW1h[29*DD];
#pragma unroll
        for (int c2=0;c2<5;c2++){
          float4 wA=wr0[c2], wB=wr1[c2];
          s0 += h[4*c2]*wA.x+h[4*c2+1]*wA.y+h[4*c2+2]*wA.z+h[4*c2+3]*wA.w;
          s1 += h[4*c2]*wB.x+h[4*c2+1]*wB.y+h[4*c2+2]*wB.z+h[4*c2+3]*wB.w;
        }
      }
      z += fmaxf(s0,0.f)*sW2[28] + fmaxf(s1,0.f)*sW2[29];
    }
    float score = 1.f/(1.f+__expf(-z));

    // transform: RT = RW[sel][r] + TW[sel][ta] (hot L1/L2 tables) + optional h @ Wsel (LDS)
    const float4* rwp=(const float4*)(RW + ((size_t)(sel*nrel+r))*DD);
    const float4* twp=(const float4*)(TW + ((size_t)(sel*ntime+ta))*DD);
#pragma unroll
    for (int c=0;c<5;c++){
      float4 a4=rwp[c], b4=twp[c];
      float mv[4]={a4.x+b4.x, a4.y+b4.y, a4.z+b4.z, a4.w+b4.w};
      if (HASH){
#pragma unroll
        for (int u=0;u<4;u++){
          const float4* wr=(const float4*)&sW3[sel*DD*DD+(4*c+u)*DD];
          float sum=mv[u];
#pragma unroll
          for (int c2=0;c2<5;c2++){ float4 w=wr[c2]; sum += h[4*c2]*w.x+h[4*c2+1]*w.y+h[4*c2+2]*w.z+h[4*c2+3]*w.w; }
          mv[u]=sum;
        }
      }
#pragma unroll
      for (int u=0;u<4;u++) m[4*c+u]=score*mv[u];
    }
#pragma unroll
    for (int i2=0;i2<10;i2++) smsg[tid*10+i2]=pkbf(m[2*i2],m[2*i2+1]);
  }
  sdst[tid] = active ? dstv : -2;
  __syncthreads();

  if (!active) return;
  bool isHead = (tid==0) ? (s_prevdst != dstv) : (sdst[tid-1] != dstv);
  if (!(isHead || tid==0)) return;
  int k=tid+1;
  for (; k<bsize && sdst[k]==dstv; ++k){
    const u32* row=&smsg[k*10];
#pragma unroll
    for (int i2=0;i2<10;i2++){
      u32 w=row[i2];
      m[2*i2]  +=__uint_as_float(w<<16);
      m[2*i2+1]+=__uint_as_float(w&0xFFFF0000u);
    }
  }
  bool crossStart = (tid==0 && !isHead);
  bool crossEnd   = (k==bsize) && (s_nextdst==dstv);
  if (crossStart || crossEnd){
    float* o = bufF + (size_t)dstv*DD;
#pragma unroll
    for (int i=0;i<DD;i++) atomicAdd(o+i, m[i]);
    if (isHead){                          // one list entry per crossing segment
      int p = atomicAdd(listc,1);
      list[p] = dstv;
    }
  } else {
    if (!FINAL){
      u32 o10[10];
#pragma unroll
      for (int i2=0;i2<10;i2++){
        float x0=m[2*i2], x1=m[2*i2+1];
        x0=fmaxf(x0,0.01f*x0); x1=fmaxf(x1,0.01f*x1);     // leaky at store
        o10[i2]=pkbf(x0,x1);
      }
      uint4* hp=(uint4*)(hout+(size_t)dstv*HROW);
      hp[0]=make_uint4(o10[0],o10[1],o10[2],o10[3]);
      hp[1]=make_uint4(o10[4],o10[5],o10[6],o10[7]);
      *((uint2*)(hp+2))=make_uint2(o10[8],o10[9]);
    } else {
      float rsum=bcls[0];
#pragma unroll
      for (int i=0;i<DD;i++){ float x=fmaxf(m[i],0.01f*m[i]); rsum += x*wcls[i]; }
      long long stride = nentp[0];
      outp[(long long)nbv[dstv]*stride + nev[dstv]] = rsum;
    }
  }
}

// ---- finish crossing segments: read f32 spill, re-zero it, emit bf16 row (or final score) ----
template<bool FINAL>
__global__ void __launch_bounds__(256) k_fixup(float* __restrict__ bufF, u16* __restrict__ hout,
   const float* __restrict__ wcls,const float* __restrict__ bcls,
   const int* __restrict__ nb,const int* __restrict__ ne,const int* __restrict__ nentp,
   float* __restrict__ out,const int* __restrict__ list,const int* __restrict__ listc){
  int c=*listc;
  for (int i=blockIdx.x*blockDim.x+threadIdx.x; i<c; i+=gridDim.x*blockDim.x){
    int n=list[i];
    float* p=bufF+(size_t)n*DD;
    float v[DD];
#pragma unroll
    for (int jj=0;jj<DD;jj++){ v[jj]=p[jj]; p[jj]=0.f; }
    if (FINAL){
      float rsum=bcls[0];
#pragma unroll
      for (int jj=0;jj<DD;jj++){ float x=fmaxf(v[jj],0.01f*v[jj]); rsum+=x*wcls[jj]; }
      long long stride=nentp[0];
      out[(long long)nb[n]*stride+ne[n]]=rsum;
    } else {
      u32 o10[10];
#pragma unroll
      for (int i2=0;i2<10;i2++){
        float x0=v[2*i2], x1=v[2*i2+1];
        x0=fmaxf(x0,0.01f*x0); x1=fmaxf(x1,0.01f*x1);
        o10[i2]=pkbf(x0,x1);
      }
      uint4* hp=(uint4*)(hout+(size_t)n*HROW);
      hp[0]=make_uint4(o10[0],o10[1],o10[2],o10[3]);
      hp[1]=make_uint4(o10[4],o10[5],o10[6],o10[7]);
      *((uint2*)(hp+2))=make_uint2(o10[8],o10[9]);
    }
  }
}

// ================= fallback (round-2 proven atomic path, f32) =================
template<bool HASH>
__global__ void __launch_bounds__(256) k_edge(
    const int* __restrict__ src, const int* __restrict__ dst,
    const int* __restrict__ rel, const int* __restrict__ qrel,
    const int* __restrict__ rtm,
    const float* __restrict__ hin, float* __restrict__ hout,
    const float* __restrict__ RT, const float* __restrict__ AR, const float* __restrict__ AQ,
    const float* __restrict__ w1, const float* __restrict__ w2, const float* __restrict__ W3,
    int E, int nrel, int ntime)
{
  __shared__ float sW1h[HID*DD];
  __shared__ float sW2[32];
  __shared__ float sW3[3*DD*DD];
  for (int t=threadIdx.x; t<HID*DD; t+=blockDim.x){ int j=t/DD,k=t-j*DD; sW1h[t]=w1[j*3*DD+k]; }
  if (threadIdx.x<HID) sW2[threadIdx.x]=w2[threadIdx.x];
  for (int t=threadIdx.x; t<3*DD*DD; t+=blockDim.x) sW3[t]=W3[t];
  __syncthreads();
  int e = blockIdx.x*blockDim.x+threadIdx.x;
  if (e>=E) return;
  int s=src[e], d=dst[e], r=rel[e], q=qrel[e], t=rtm[e];
  int sel = (t>0)?2:((t==0)?1:0);
  int ta = (t<0)?-t:t;
  float h[DD];
  if (HASH){
    load20(hin+(size_t)s*DD, h);
#pragma unroll
    for (int i=0;i<DD;i++) h[i]=fmaxf(h[i],0.01f*h[i]);
  }
  float a[HID];
  {
    const float4* ap=(const float4*)(AR+(size_t)r*32);
    const float4* qp=(const float4*)(AQ+(size_t)q*32);
#pragma unroll
    for (int c=0;c<7;c++){
      float4 x=ap[c], y=qp[c];
      a[4*c+0]=x.x+y.x; a[4*c+1]=x.y+y.y; a[4*c+2]=x.z+y.z; a[4*c+3]=x.w+y.w;
    }
    float2 x=*(const float2*)(AR+(size_t)r*32+28);
    float2 y=*(const float2*)(AQ+(size_t)q*32+28);
    a[28]=x.x+y.x; a[29]=x.y+y.y;
  }
  if (HASH){
#pragma unroll
    for (int j=0;j<HID;j++){
      const float4* wr=(const float4*)&sW1h[j*DD];
      float sum=a[j];
#pragma unroll
      for (int c=0;c<5;c++){ float4 w=wr[c]; sum += h[4*c]*w.x+h[4*c+1]*w.y+h[4*c+2]*w.z+h[4*c+3]*w.w; }
      a[j]=sum;
    }
  }
  float z=0.f;
#pragma unroll
  for (int j=0;j<HID;j++) z += fmaxf(a[j],0.f)*sW2[j];
  float score = 1.f/(1.f+__expf(-z));
  float tr[DD];
  load20(RT + ((size_t)(sel*nrel+r)*ntime + ta)*DD, tr);
  if (HASH){
    const float* Ws = sW3 + sel*DD*DD;
#pragma unroll
    for (int i=0;i<DD;i++){
      const float4* wr=(const float4*)(Ws+i*DD);
      float sum=tr[i];
#pragma unroll
      for (int c=0;c<5;c++){ float4 w=wr[c]; sum += h[4*c]*w.x+h[4*c+1]*w.y+h[4*c+2]*w.z+h[4*c+3]*w.w; }
      tr[i]=sum;
    }
  }
  float* o = hout + (size_t)d*DD;
#pragma unroll
  for (int i=0;i<DD;i++) atomicAdd(o+i, score*tr[i]);
}

__global__ void k_result(const float* __restrict__ h, const float* __restrict__ wcls,
                         const float* __restrict__ bcls, float* __restrict__ res, int N){
  int i = blockIdx.x*blockDim.x+threadIdx.x;
  if (i>=N) return;
  float acc = bcls[0];
  const float4* q=(const float4*)(h+(size_t)i*DD);
#pragma unroll
  for (int c=0;c<5;c++){
    float4 v=q[c];
    float x0=fmaxf(v.x,0.01f*v.x), x1=fmaxf(v.y,0.01f*v.y);
    float x2=fmaxf(v.z,0.01f*v.z), x3=fmaxf(v.w,0.01f*v.w);
    acc += x0*wcls[4*c]+x1*wcls[4*c+1]+x2*wcls[4*c+2]+x3*wcls[4*c+3];
  }
  res[i]=acc;
}

__global__ void k_scatter(const float* __restrict__ res, const int* __restrict__ nb,
                          const int* __restrict__ ne, const int* __restrict__ nentp,
                          float* __restrict__ out, int N){
  int i=blockIdx.x*blockDim.x+threadIdx.x;
  if (i>=N) return;
  long long stride = nentp[0];
  out[(long long)nb[i]*stride + ne[i]] = res[i];
}

extern "C" void kernel_launch(void* const* d_in, const int* in_sizes, int n_in,
                              void* d_out, int out_size, void* d_ws, size_t ws_size,
                              hipStream_t stream){
  const int*   src =(const int*)d_in[0];
  const int*   dst =(const int*)d_in[1];
  const int*   rel =(const int*)d_in[2];
  const int*   qrel=(const int*)d_in[3];
  const int*   rtm =(const int*)d_in[4];
  const int*   nb  =(const int*)d_in[5];
  const int*   ne  =(const int*)d_in[6];
  const float* rela=(const float*)d_in[7];
  const float* timee=(const float*)d_in[8];
  const float* w1  =(const float*)d_in[9];
  const float* w2  =(const float*)d_in[10];
  const float* wp  =(const float*)d_in[11];
  const float* wn  =(const float*)d_in[12];
  const float* wf  =(const float*)d_in[13];
  const float* wcls=(const float*)d_in[14];
  const float* bcls=(const float*)d_in[15];
  const int*   nentp=(const int*)d_in[17];

  const int Lc=3;
  int LE=in_sizes[0]; int E=LE/Lc;
  int N=in_sizes[5];
  int nrel=in_sizes[7]/DD;
  int ntime=in_sizes[8]/DD;

  auto al=[](size_t x){ return (x+(size_t)255)&~(size_t)255; };
  size_t szBufB=al((size_t)N*HROW*2);              // bf16 hidden, 64 B rows
  size_t szBufF=al((size_t)N*DD*4);                // f32 crossing spill
  size_t szBuf =al((size_t)N*DD*4);                // fallback f32 bufs
  size_t szRW  =al((size_t)3*nrel*DD*4);           // rela @ Wsel (48 KB)
  size_t szTW  =al((size_t)3*ntime*DD*4);          // time @ Wsel (88 KB)
  size_t szRTf =al((size_t)3*nrel*ntime*DD*4);     // fallback f32 RT
  size_t szA   =al((size_t)nrel*32*4);
  size_t szW3  =al((size_t)3*DD*DD*4);
  size_t szRow =al((size_t)Lc*((size_t)N+1)*4);
  size_t szRank=al((size_t)LE*4);
  size_t szCnt =al((size_t)Lc*N*4);
  size_t szRecs=al((size_t)LE*16);
  size_t szPart=al((size_t)NB_SCAN*4);
  size_t szList=al((size_t)(131072+16)*4);
  size_t need = 2*szBufB+szBufF+szRW+szTW+2*szA+szW3+szRow+szRank+szCnt+szRecs+szPart+szList;

  dim3 blk(256);
  int prepTot = (3*DD*DD > nrel*HID) ? 3*DD*DD : nrel*HID;
  int rtTot=3*nrel*ntime;
  int rwtwTot = 3*ntime*DD;  // >= 3*nrel*DD

  if (ws_size >= need){
    char* base=(char*)d_ws;
    size_t off=0;
    u16*   b0 =(u16*)(base+off);   off+=szBufB;
    u16*   b1 =(u16*)(base+off);   off+=szBufB;
    float* bufF=(float*)(base+off); off+=szBufF;
    float* RW  =(float*)(base+off); off+=szRW;
    float* TW  =(float*)(base+off); off+=szTW;
    float* AR  =(float*)(base+off); off+=szA;
    float* AQ  =(float*)(base+off); off+=szA;
    float* W3  =(float*)(base+off); off+=szW3;
    int*   rowptr=(int*)(base+off); off+=szRow;     // Lc*(N+1)
    int*   rank=(int*)(base+off);  off+=szRank;
    int*   cnt =(int*)(base+off);  off+=szCnt;      // Lc*N
    int4*  recs=(int4*)(base+off); off+=szRecs;
    int*   part=(int*)(base+off);  off+=szPart;
    int*   listc=(int*)(base+off);
    int*   list =listc+16;          off+=szList;

    float* dout=(float*)d_out;

    (void)hipMemsetAsync(cnt,0,(size_t)Lc*N*4,stream);
    k_prep<<<dim3((prepTot+255)/256),blk,0,stream>>>(rela,w1,wp,wn,wf,W3,AR,AQ,nrel);
    k_rwtw<<<dim3((rwtwTot+255)/256),blk,0,stream>>>(rela,timee,W3,RW,TW,nrel,ntime);

    size_t nd4=(size_t)out_size>>2;
    size_t nbB4=(size_t)N*HROW*2/16;     // uint4 count per bf16 buf
    size_t nf4=(size_t)N*DD/4;
    k_pre<<<dim3(8192),blk,0,stream>>>(dst,cnt,rank,E,(float4*)dout,nd4,
                                       (uint4*)b0,(uint4*)b1,nbB4,(float4*)bufF,nf4);

    int C=(N+NB_SCAN-1)/NB_SCAN;
    int LB=(E+255)/256;
    int H=(LB+1)/2;

    for (int l=0;l<Lc;++l){
      int* cnt_l = cnt + (size_t)l*N;
      int* row_l = rowptr + (size_t)l*(N+1);
      k_scan_part<<<dim3(NB_SCAN),blk,0,stream>>>(cnt_l,part,N,C);
      k_scan_top<<<dim3(1),dim3(NB_SCAN),0,stream>>>(part,listc);
      k_scan_write<<<dim3(NB_SCAN),blk,0,stream>>>(cnt_l,part,row_l,N,C);
      size_t eo=(size_t)l*E;
      int xb = (l==0)?1024:0;
      k_scat<<<dim3(xb+LB),blk,0,stream>>>(src+eo,dst+eo,rel+eo,qrel+eo,rtm+eo,
          rank+eo,row_l,recs+eo,E,xb,dout,nb,ne,nentp,bcls,N);
      if (l==0){
        k_fused<false,true,false><<<dim3(3*H),blk,0,stream>>>(recs,nullptr,b0,bufF,
            RW,TW,AR,AQ,w1,w2,W3,E,nrel,ntime,
            dst+(size_t)E,cnt+(size_t)N,rank+(size_t)E,E,
            nullptr,nullptr,nullptr,nullptr,nullptr,nullptr,list,listc);
        k_fixup<false><<<dim3(128),blk,0,stream>>>(bufF,b0,wcls,bcls,nb,ne,nentp,dout,list,listc);
      } else if (l==1){
        k_fused<true,true,false><<<dim3(3*H),blk,0,stream>>>(recs+(size_t)E,b0,b1,bufF,
            RW,TW,AR,AQ,w1,w2,W3,E,nrel,ntime,
            dst+(size_t)2*E,cnt+(size_t)2*N,rank+(size_t)2*E,E,
            nullptr,nullptr,nullptr,nullptr,nullptr,nullptr,list,listc);
        k_fixup<false><<<dim3(128),blk,0,stream>>>(bufF,b1,wcls,bcls,nb,ne,nentp,dout,list,listc);
      } else {
        k_fused<true,false,true><<<dim3(LB),blk,0,stream>>>(recs+(size_t)2*E,b1,nullptr,bufF,
            RW,TW,AR,AQ,w1,w2,W3,E,nrel,ntime,
            nullptr,nullptr,nullptr,0,
            wcls,bcls,nb,ne,nentp,dout,list,listc);
        k_fixup<true><<<dim3(128),blk,0,stream>>>(bufF,nullptr,wcls,bcls,nb,ne,nentp,dout,list,listc);
      }
    }
  } else {
    // fallback: proven round-2 atomic path (scratch carved from d_out, res in ws)
    char* base=(char*)d_out; float* res=(float*)d_ws;
    size_t off=0;
    float* buf0=(float*)(base+off); off+=szBuf;
    float* buf1=(float*)(base+off); off+=szBuf;
    float* RT  =(float*)(base+off); off+=szRTf;
    float* AR  =(float*)(base+off); off+=szA;
    float* AQ  =(float*)(base+off); off+=szA;
    float* W3  =(float*)(base+off); off+=szW3;
    k_prep<<<dim3((prepTot+255)/256),blk,0,stream>>>(rela,w1,wp,wn,wf,W3,AR,AQ,nrel);
    k_rt<<<dim3((rtTot+255)/256),blk,0,stream>>>(rela,timee,W3,RT,nrel,ntime);
    dim3 egrid((E+255)/256);
    dim3 ngrid((N+255)/256);
    (void)hipMemsetAsync(buf0,0,(size_t)N*DD*4,stream);
    k_edge<false><<<egrid,blk,0,stream>>>(src,dst,rel,qrel,rtm,nullptr,buf0,RT,AR,AQ,w1,w2,W3,E,nrel,ntime);
    (void)hipMemsetAsync(buf1,0,(size_t)N*DD*4,stream);
    k_edge<true><<<egrid,blk,0,stream>>>(src+(size_t)E,dst+(size_t)E,rel+(size_t)E,qrel+(size_t)E,rtm+(size_t)E,
                                         buf0,buf1,RT,AR,AQ,w1,w2,W3,E,nrel,ntime);
    (void)hipMemsetAsync(buf0,0,(size_t)N*DD*4,stream);
    k_edge<true><<<egrid,blk,0,stream>>>(src+(size_t)2*E,dst+(size_t)2*E,rel+(size_t)2*E,qrel+(size_t)2*E,rtm+(size_t)2*E,
                                         buf1,buf0,RT,AR,AQ,w1,w2,W3,E,nrel,ntime);
    k_result<<<ngrid,blk,0,stream>>>(buf0,wcls,bcls,res,N);
    (void)hipMemsetAsync(d_out,0,(size_t)out_size*sizeof(float),stream);
    k_scatter<<<ngrid,blk,0,stream>>>(res,nb,ne,nentp,(float*)d_out,N);
  }
}